// Round 15
// baseline (225.862 us; speedup 1.0000x reference)
//
#include <hip/hip_runtime.h>
#include <hip/hip_fp16.h>

#define INCH   128
#define HEADS1 8
#define HID1   16
#define C1     128   // HEADS1*HID1
#define C2     64
#define NEG_SLOPE 0.2f
#define SB     256   // scan blocks / threads

using f16x8 = __attribute__((ext_vector_type(8))) _Float16;
using f32x4 = __attribute__((ext_vector_type(4))) float;

__device__ __forceinline__ float lrelu(float v) { return v >= 0.f ? v : NEG_SLOPE * v; }
// byte-offset swizzle within a 256B LDS row (rows are 128 fp16)
__device__ __forceinline__ int swzA(int row, int byteInRow) {
  return (row << 8) | (byteInRow ^ ((row & 15) << 4));
}

// ---------------- prep: W1/W2 transpose->fp16, dst histogram ----------------

__global__ void prep_kernel(const float* __restrict__ W1, __half* __restrict__ W1t,
                            const float* __restrict__ W2, __half* __restrict__ W2t,
                            const int* __restrict__ dst, int* __restrict__ deg,
                            int tB, int E) {
  const int b = blockIdx.x, t = threadIdx.x;
  if (b < tB) {
    int id = b * 256 + t;
    if (id < 128 * 128) {
      int col = id >> 7, k = id & 127;
      W1t[id] = __float2half(W1[k * 128 + col]);
    } else if (id < 128 * 128 + 64 * 128) {
      int idx = id - 128 * 128;
      int col = idx >> 7, k = idx & 127;
      W2t[idx] = __float2half(W2[k * 64 + col]);
    }
  } else {
    int e = (b - tB) * 256 + t;
    if (e < E) atomicAdd(&deg[dst[e]], 1);
  }
}

// ---------------- CSR build (by destination, 16-padded segments) ----------------

// stage 1: per-block reduction of PADDED degrees; also zeroes cursor.
__global__ void scan1_kernel(const int* __restrict__ deg, int* __restrict__ partial,
                             int* __restrict__ cursor, int N) {
  __shared__ int sh[SB];
  const int b = blockIdx.x, t = threadIdx.x;
  const int chunk = (N + SB - 1) / SB;
  const int lo = b * chunk, hi = min(lo + chunk, N);
  int s = 0;
  for (int i = lo + t; i < hi; i += SB) {
    s += (deg[i] + 15) & ~15;
    cursor[i] = 0;
  }
  sh[t] = s;
  __syncthreads();
  for (int off = SB / 2; off; off >>= 1) {
    if (t < off) sh[t] += sh[t + off];
    __syncthreads();
  }
  if (t == 0) partial[b] = sh[0];
}

// stage 2+3 fused: each block locally scans the 256 partials, then scans its chunk.
__global__ void scan3_kernel(const int* __restrict__ deg, const int* __restrict__ partial,
                             int* __restrict__ row_start, int N) {
  __shared__ int pref[SB];
  __shared__ int sh[SB];
  const int b = blockIdx.x, t = threadIdx.x;
  int pv = partial[t];
  pref[t] = pv;
  __syncthreads();
  for (int off = 1; off < SB; off <<= 1) {
    int u = (t >= off) ? pref[t - off] : 0;
    __syncthreads();
    pref[t] += u;
    __syncthreads();
  }
  const int chunk = (N + SB - 1) / SB;
  const int lo = b * chunk, hi = min(lo + chunk, N);
  int run = (b == 0) ? 0 : pref[b - 1];
  for (int base = lo; base < hi; base += SB) {
    int i = base + t;
    int v = (i < hi) ? ((deg[i] + 15) & ~15) : 0;
    sh[t] = v;
    __syncthreads();
    for (int off = 1; off < SB; off <<= 1) {
      int u = (t >= off) ? sh[t - off] : 0;
      __syncthreads();
      sh[t] += u;
      __syncthreads();
    }
    if (i < hi) row_start[i] = run + sh[t] - v;
    run += sh[SB - 1];
    __syncthreads();
  }
  if (b == SB - 1 && t == 0) row_start[N] = run;
}

// zero-LDS scatter fill (high occupancy)
__global__ void fill_kernel(const int* __restrict__ src, const int* __restrict__ dst,
                            const int* __restrict__ row_start, int* __restrict__ cursor,
                            int* __restrict__ src_sorted, int E) {
  int e = blockIdx.x * blockDim.x + threadIdx.x;
  if (e >= E) return;
  int d = dst[e];
  int slot = row_start[d] + atomicAdd(&cursor[d], 1);
  src_sorted[slot] = src[e];
}

// ---------------- MFMA GEMMs ----------------
// gemm1: [M x 128] x [128 x 128]; x converted f32->fp16 inline during LDS staging.
__global__ __launch_bounds__(256) void gemm1_mfma(
    const float* __restrict__ x, const __half* __restrict__ W1t,
    const float* __restrict__ a_src, const float* __restrict__ a_dst,
    __half* __restrict__ h1, float* __restrict__ s1, float* __restrict__ d1, int M) {
  __shared__ unsigned char As[16384];   // 64 x 128 fp16, swizzled
  __shared__ unsigned char Bs[32768];   // 128 x 128 fp16 (col-major W1), swizzled
  const int t = threadIdx.x;
  const int m0 = blockIdx.x * 64;
  for (int c = t; c < 1024; c += 256) {
    int row = c >> 4, seg = c & 15;     // seg = 8 columns (16B of halves)
    int gr = m0 + row;
    uint4 v = make_uint4(0, 0, 0, 0);
    if (gr < M) {
      const float4* px = (const float4*)&x[(size_t)gr * 128 + (seg << 3)];
      float4 v0 = px[0], v1 = px[1];
      __half2 ha = __floats2half2_rn(v0.x, v0.y);
      __half2 hb = __floats2half2_rn(v0.z, v0.w);
      __half2 hc = __floats2half2_rn(v1.x, v1.y);
      __half2 hd = __floats2half2_rn(v1.z, v1.w);
      v = make_uint4(*(unsigned*)&ha, *(unsigned*)&hb, *(unsigned*)&hc, *(unsigned*)&hd);
    }
    *(uint4*)(As + swzA(row, seg << 4)) = v;
  }
  for (int c = t; c < 2048; c += 256) {
    int row = c >> 4, seg = c & 15;
    uint4 v = ((const uint4*)W1t)[(row << 4) + seg];
    *(uint4*)(Bs + swzA(row, seg << 4)) = v;
  }
  __syncthreads();
  const int l = t & 63, wid = t >> 6;
  const int c16 = l & 15;
  const int kOff = (l >> 4) << 4;
  const int rA = (wid << 4) | c16;
  f16x8 a[4];
#pragma unroll
  for (int kb = 0; kb < 4; ++kb)
    a[kb] = *(const f16x8*)(As + swzA(rA, (kb << 6) + kOff));
#pragma unroll
  for (int ct = 0; ct < 8; ++ct) {        // ct == head (HID1 == 16)
    const int rB = (ct << 4) | c16;
    f32x4 acc = {0.f, 0.f, 0.f, 0.f};
#pragma unroll
    for (int kb = 0; kb < 4; ++kb) {
      f16x8 b = *(const f16x8*)(Bs + swzA(rB, (kb << 6) + kOff));
      acc = __builtin_amdgcn_mfma_f32_16x16x32_f16(a[kb], b, acc, 0, 0, 0);
    }
    const int colg = (ct << 4) + c16;
    const float asv = a_src[colg], adv = a_dst[colg];
#pragma unroll
    for (int i = 0; i < 4; ++i) {
      const int n = m0 + (wid << 4) + ((l >> 4) << 2) + i;
      float v = acc[i];
      float sv = v * asv, dv = v * adv;
      sv += __shfl_xor(sv, 1); sv += __shfl_xor(sv, 2);
      sv += __shfl_xor(sv, 4); sv += __shfl_xor(sv, 8);
      dv += __shfl_xor(dv, 1); dv += __shfl_xor(dv, 2);
      dv += __shfl_xor(dv, 4); dv += __shfl_xor(dv, 8);
      if (n < M) {
        h1[(unsigned)(n << 7) + colg] = __float2half(v);
        if (c16 == 0) { s1[n * HEADS1 + ct] = sv; d1[n * HEADS1 + ct] = dv; }
      }
    }
  }
}

// gemm2: [M x 128] x [128 x 64]
__global__ __launch_bounds__(256) void gemm2_mfma(
    const __half* __restrict__ x2h, const __half* __restrict__ W2t,
    const float* __restrict__ a_src, const float* __restrict__ a_dst,
    __half* __restrict__ h2, float* __restrict__ s2, float* __restrict__ d2, int M) {
  __shared__ unsigned char As[16384];   // 64 x 128 fp16
  __shared__ unsigned char Bs[16384];   // 64 x 128 fp16 (col-major W2)
  const int t = threadIdx.x;
  const int m0 = blockIdx.x * 64;
  for (int c = t; c < 1024; c += 256) {
    int row = c >> 4, seg = c & 15;
    int gr = m0 + row;
    uint4 v = make_uint4(0, 0, 0, 0);
    if (gr < M) v = ((const uint4*)x2h)[(unsigned)(gr << 4) + seg];
    *(uint4*)(As + swzA(row, seg << 4)) = v;
  }
  for (int c = t; c < 1024; c += 256) {
    int row = c >> 4, seg = c & 15;
    uint4 v = ((const uint4*)W2t)[(row << 4) + seg];
    *(uint4*)(Bs + swzA(row, seg << 4)) = v;
  }
  __syncthreads();
  const int l = t & 63, wid = t >> 6;
  const int c16 = l & 15;
  const int kOff = (l >> 4) << 4;
  const int rA = (wid << 4) | c16;
  f16x8 a[4];
#pragma unroll
  for (int kb = 0; kb < 4; ++kb)
    a[kb] = *(const f16x8*)(As + swzA(rA, (kb << 6) + kOff));
  float svp[4] = {0.f, 0.f, 0.f, 0.f};
  float dvp[4] = {0.f, 0.f, 0.f, 0.f};
#pragma unroll
  for (int ct = 0; ct < 4; ++ct) {
    const int rB = (ct << 4) | c16;
    f32x4 acc = {0.f, 0.f, 0.f, 0.f};
#pragma unroll
    for (int kb = 0; kb < 4; ++kb) {
      f16x8 b = *(const f16x8*)(Bs + swzA(rB, (kb << 6) + kOff));
      acc = __builtin_amdgcn_mfma_f32_16x16x32_f16(a[kb], b, acc, 0, 0, 0);
    }
    const int colg = (ct << 4) + c16;
    const float asv = a_src[colg], adv = a_dst[colg];
#pragma unroll
    for (int i = 0; i < 4; ++i) {
      const int n = m0 + (wid << 4) + ((l >> 4) << 2) + i;
      float v = acc[i];
      svp[i] += v * asv;
      dvp[i] += v * adv;
      if (n < M) h2[(unsigned)(n << 6) + colg] = __float2half(v);
    }
  }
#pragma unroll
  for (int i = 0; i < 4; ++i) {
    float sv = svp[i], dv = dvp[i];
    sv += __shfl_xor(sv, 1); sv += __shfl_xor(sv, 2);
    sv += __shfl_xor(sv, 4); sv += __shfl_xor(sv, 8);
    dv += __shfl_xor(dv, 1); dv += __shfl_xor(dv, 2);
    dv += __shfl_xor(dv, 4); dv += __shfl_xor(dv, 8);
    const int n = m0 + (wid << 4) + ((l >> 4) << 2) + i;
    if (c16 == 0 && n < M) { s2[n] = sv; d2[n] = dv; }
  }
}

// ---------------- Fused softmax + wide aggregation ----------------
// 16-padded CSR segments (src_sorted pre-zeroed): pad-slot loads hit node 0's
// row and carry weight 0. 32-slot clamp-free prefetch covers deg<=32 (~all of
// a Poisson(16) graph) so every row gather is in flight during the logit pass.
// Softmax max-pass dropped (shift-invariant; logits O(1..8) here).
// Persistent launch: 2048 blocks x 4 waves = 32 waves/CU.
__global__ __launch_bounds__(256) void layer1_agg(
    const int* __restrict__ row_start, const int* __restrict__ deg,
    const int* __restrict__ src_sorted,
    const float* __restrict__ s1, const float* __restrict__ d1,
    const __half* __restrict__ h1, const float* __restrict__ b1,
    __half* __restrict__ x2h, int N) {
  __shared__ float wlds[4][64][8];   // [wave][slot][head]
  const int wv = threadIdx.x >> 6;
  const int lane = threadIdx.x & 63;
  const int le = lane >> 3, h = lane & 7;     // phase 1
  const int es = lane >> 4, cl = lane & 15;   // phase 2
  const int hh = cl >> 1;
  const uint4* __restrict__ h1v = (const uint4*)h1;
  const int waveId = blockIdx.x * 4 + wv;
  const int stride = gridDim.x * 4;
  for (int n = waveId; n < N; n += stride) {
    const int lo = row_start[n];
    const int total = deg[n];
    const float dv = d1[n * HEADS1 + h];
    float z = 0.f;
    float acc[8] = {0.f, 0.f, 0.f, 0.f, 0.f, 0.f, 0.f, 0.f};
    for (int off0 = 0; off0 < total; off0 += 64) {
      const int base = lo + off0;
      const int cnt = min(64, total - off0);
      // ---- phase 0: issue row gathers for the first 32 slots (pad-safe; reads
      //      past the segment stay inside the zero-initialized src_sorted array)
      const int ps0 = src_sorted[base + es];
      const int ps1 = src_sorted[base + 4 + es];
      const int ps2 = src_sorted[base + 8 + es];
      const int ps3 = src_sorted[base + 12 + es];
      const int ps4 = src_sorted[base + 16 + es];
      const int ps5 = src_sorted[base + 20 + es];
      const int ps6 = src_sorted[base + 24 + es];
      const int ps7 = src_sorted[base + 28 + es];
      const uint4 pf0 = h1v[(unsigned)(ps0 << 4) + cl];
      const uint4 pf1 = h1v[(unsigned)(ps1 << 4) + cl];
      const uint4 pf2 = h1v[(unsigned)(ps2 << 4) + cl];
      const uint4 pf3 = h1v[(unsigned)(ps3 << 4) + cl];
      const uint4 pf4 = h1v[(unsigned)(ps4 << 4) + cl];
      const uint4 pf5 = h1v[(unsigned)(ps5 << 4) + cl];
      const uint4 pf6 = h1v[(unsigned)(ps6 << 4) + cl];
      const uint4 pf7 = h1v[(unsigned)(ps7 << 4) + cl];
      // ---- phase 1: w = exp(logit) -> LDS (zeros for pad slots)
      const int rmax = (cnt + 7) >> 3;   // wave-uniform
      for (int r = 0; r < rmax; ++r) {
        const int j = (r << 3) + le;
        float w = 0.f;
        if (j < cnt) w = __expf(lrelu(s1[src_sorted[base + j] * HEADS1 + h] + dv));
        wlds[wv][j][h] = w;
        z += w;
      }
      // ---- phase 2a: consume prefetched rows; guards are wave-uniform and
      //      skip wlds slots that phase 1 never wrote.
      {
        const float wA = wlds[wv][es][hh];
        const float wB = wlds[wv][4 + es][hh];
        const __half2* pA = (const __half2*)&pf0;
        const __half2* pB = (const __half2*)&pf1;
#pragma unroll
        for (int k = 0; k < 4; ++k) {
          float2 a2 = __half22float2(pA[k]);
          float2 b2v = __half22float2(pB[k]);
          acc[2 * k]     += wA * a2.x + wB * b2v.x;
          acc[2 * k + 1] += wA * a2.y + wB * b2v.y;
        }
      }
      if (cnt > 8) {
        const float wA = wlds[wv][8 + es][hh];
        const float wB = wlds[wv][12 + es][hh];
        const __half2* pA = (const __half2*)&pf2;
        const __half2* pB = (const __half2*)&pf3;
#pragma unroll
        for (int k = 0; k < 4; ++k) {
          float2 a2 = __half22float2(pA[k]);
          float2 b2v = __half22float2(pB[k]);
          acc[2 * k]     += wA * a2.x + wB * b2v.x;
          acc[2 * k + 1] += wA * a2.y + wB * b2v.y;
        }
      }
      if (cnt > 16) {
        const float wA = wlds[wv][16 + es][hh];
        const float wB = wlds[wv][20 + es][hh];
        const __half2* pA = (const __half2*)&pf4;
        const __half2* pB = (const __half2*)&pf5;
#pragma unroll
        for (int k = 0; k < 4; ++k) {
          float2 a2 = __half22float2(pA[k]);
          float2 b2v = __half22float2(pB[k]);
          acc[2 * k]     += wA * a2.x + wB * b2v.x;
          acc[2 * k + 1] += wA * a2.y + wB * b2v.y;
        }
      }
      if (cnt > 24) {
        const float wA = wlds[wv][24 + es][hh];
        const float wB = wlds[wv][28 + es][hh];
        const __half2* pA = (const __half2*)&pf6;
        const __half2* pB = (const __half2*)&pf7;
#pragma unroll
        for (int k = 0; k < 4; ++k) {
          float2 a2 = __half22float2(pA[k]);
          float2 b2v = __half22float2(pB[k]);
          acc[2 * k]     += wA * a2.x + wB * b2v.x;
          acc[2 * k + 1] += wA * a2.y + wB * b2v.y;
        }
      }
      // ---- phase 2b: remaining slots (deg > 32 within this chunk; rare)
      for (int i = 32; i < cnt; i += 8) {
        const int jA = i + es, jB = i + 4 + es;
        const float wA = wlds[wv][jA][hh];
        const float wB = wlds[wv][jB][hh];
        const int sA = src_sorted[base + jA];
        const int sB = src_sorted[base + jB];
        const uint4 fA = h1v[(unsigned)(sA << 4) + cl];
        const uint4 fB = h1v[(unsigned)(sB << 4) + cl];
        const __half2* pA = (const __half2*)&fA;
        const __half2* pB = (const __half2*)&fB;
#pragma unroll
        for (int k = 0; k < 4; ++k) {
          float2 a2 = __half22float2(pA[k]);
          float2 b2v = __half22float2(pB[k]);
          acc[2 * k]     += wA * a2.x + wB * b2v.x;
          acc[2 * k + 1] += wA * a2.y + wB * b2v.y;
        }
      }
    }
    // finalize: z per (le,h) partial; reduce over le (lanes with same h)
    z += __shfl_xor(z, 8); z += __shfl_xor(z, 16); z += __shfl_xor(z, 32);
    const float zsel = __shfl(z, hh);   // lane hh holds head hh's total
#pragma unroll
    for (int k = 0; k < 8; ++k) {
      acc[k] += __shfl_xor(acc[k], 16);
      acc[k] += __shfl_xor(acc[k], 32);
    }
    if (es == 0) {
      const float zinv = 1.f / (zsel + 1e-16f);
      __half2 o[4];
#pragma unroll
      for (int k = 0; k < 4; ++k) {
        float ox = acc[2 * k] * zinv + b1[(cl << 3) + 2 * k];
        float oy = acc[2 * k + 1] * zinv + b1[(cl << 3) + 2 * k + 1];
        ox = ox > 0.f ? ox : expm1f(ox);
        oy = oy > 0.f ? oy : expm1f(oy);
        o[k] = __floats2half2_rn(ox, oy);
      }
      ((uint4*)x2h)[(unsigned)(n << 4) + cl] = *(const uint4*)o;
    }
  }
}

// layer2: one wave per node (grid-stride), 1 head; prefetch first 32 slots
// (pad-safe). Weights live in registers, shared by shuffle (0 for pad lanes).
__global__ __launch_bounds__(256) void layer2_agg(
    const int* __restrict__ row_start, const int* __restrict__ deg,
    const int* __restrict__ src_sorted,
    const float* __restrict__ s2, const float* __restrict__ d2,
    const __half* __restrict__ h2, const float* __restrict__ b2,
    float* __restrict__ out, int N) {
  const int wv = threadIdx.x >> 6;
  const int lane = threadIdx.x & 63;
  const int es = lane >> 3, cl = lane & 7;
  const uint4* __restrict__ h2v = (const uint4*)h2;
  const int waveId = blockIdx.x * 4 + wv;
  const int stride = gridDim.x * 4;
  for (int n = waveId; n < N; n += stride) {
    const int lo = row_start[n];
    const int total = deg[n];
    const float dv = d2[n];
    float z = 0.f;
    float acc[8] = {0.f, 0.f, 0.f, 0.f, 0.f, 0.f, 0.f, 0.f};
    for (int off0 = 0; off0 < total; off0 += 64) {
      const int base = lo + off0;
      const int cnt = min(64, total - off0);
      // ---- phase 0: prefetch rows for the first 32 slots (pad-safe)
      const int ps0 = src_sorted[base + es];
      const int ps1 = src_sorted[base + 8 + es];
      const int ps2 = src_sorted[base + 16 + es];
      const int ps3 = src_sorted[base + 24 + es];
      const uint4 pf0 = h2v[(unsigned)(ps0 << 3) + cl];
      const uint4 pf1 = h2v[(unsigned)(ps1 << 3) + cl];
      const uint4 pf2 = h2v[(unsigned)(ps2 << 3) + cl];
      const uint4 pf3 = h2v[(unsigned)(ps3 << 3) + cl];
      // ---- phase 1 (w = 0 for lanes >= cnt)
      float w = 0.f;
      if (lane < cnt) w = __expf(lrelu(s2[src_sorted[base + lane]] + dv));
      z += w;
      // ---- phase 2a: consume prefetched (slots 0..31)
      {
        const float wA = __shfl(w, es);
        const float wB = __shfl(w, 8 + es);
        const __half2* pA = (const __half2*)&pf0;
        const __half2* pB = (const __half2*)&pf1;
#pragma unroll
        for (int k = 0; k < 4; ++k) {
          float2 a2 = __half22float2(pA[k]);
          float2 b2v = __half22float2(pB[k]);
          acc[2 * k]     += wA * a2.x + wB * b2v.x;
          acc[2 * k + 1] += wA * a2.y + wB * b2v.y;
        }
      }
      if (cnt > 16) {
        const float wA = __shfl(w, 16 + es);
        const float wB = __shfl(w, 24 + es);
        const __half2* pA = (const __half2*)&pf2;
        const __half2* pB = (const __half2*)&pf3;
#pragma unroll
        for (int k = 0; k < 4; ++k) {
          float2 a2 = __half22float2(pA[k]);
          float2 b2v = __half22float2(pB[k]);
          acc[2 * k]     += wA * a2.x + wB * b2v.x;
          acc[2 * k + 1] += wA * a2.y + wB * b2v.y;
        }
      }
      // ---- phase 2b: remaining slots (deg > 32 within this chunk; rare)
      for (int i = 32; i < cnt; i += 16) {
        const int jA = i + es, jB = i + 8 + es;
        const float wA = __shfl(w, jA);
        const float wB = __shfl(w, jB);
        const int sA = src_sorted[base + jA];
        const int sB = src_sorted[base + jB];
        const uint4 fA = h2v[(unsigned)(sA << 3) + cl];
        const uint4 fB = h2v[(unsigned)(sB << 3) + cl];
        const __half2* pA = (const __half2*)&fA;
        const __half2* pB = (const __half2*)&fB;
#pragma unroll
        for (int k = 0; k < 4; ++k) {
          float2 a2 = __half22float2(pA[k]);
          float2 b2v = __half22float2(pB[k]);
          acc[2 * k]     += wA * a2.x + wB * b2v.x;
          acc[2 * k + 1] += wA * a2.y + wB * b2v.y;
        }
      }
    }
#pragma unroll
    for (int off = 1; off < 64; off <<= 1) z += __shfl_xor(z, off);
#pragma unroll
    for (int k = 0; k < 8; ++k) {
      acc[k] += __shfl_xor(acc[k], 8);
      acc[k] += __shfl_xor(acc[k], 16);
      acc[k] += __shfl_xor(acc[k], 32);
    }
    if (es == 0) {
      const float zinv = 1.f / (z + 1e-16f);
      float4 o0, o1;
      o0.x = acc[0] * zinv + b2[(cl << 3) + 0];
      o0.y = acc[1] * zinv + b2[(cl << 3) + 1];
      o0.z = acc[2] * zinv + b2[(cl << 3) + 2];
      o0.w = acc[3] * zinv + b2[(cl << 3) + 3];
      o1.x = acc[4] * zinv + b2[(cl << 3) + 4];
      o1.y = acc[5] * zinv + b2[(cl << 3) + 5];
      o1.z = acc[6] * zinv + b2[(cl << 3) + 6];
      o1.w = acc[7] * zinv + b2[(cl << 3) + 7];
      float4* po = (float4*)&out[(unsigned)(n << 6) + (cl << 3)];
      po[0] = o0;
      po[1] = o1;
    }
  }
}

extern "C" void kernel_launch(void* const* d_in, const int* in_sizes, int n_in,
                              void* d_out, int out_size, void* d_ws, size_t ws_size,
                              hipStream_t stream) {
  const float* x      = (const float*)d_in[0];
  const int*   ei     = (const int*)d_in[1];
  const float* W1     = (const float*)d_in[2];
  const float* a_src1 = (const float*)d_in[3];
  const float* a_dst1 = (const float*)d_in[4];
  const float* b1     = (const float*)d_in[5];
  const float* W2     = (const float*)d_in[6];
  const float* a_src2 = (const float*)d_in[7];
  const float* a_dst2 = (const float*)d_in[8];
  const float* b2     = (const float*)d_in[9];
  float* out = (float*)d_out;

  const int N = in_sizes[0] / INCH;
  const int E = in_sizes[1] / 2;
  const int* src = ei;
  const int* dst = ei + E;
  const int EPAD = E + 16 * N;   // upper bound on padded edge count (+ slack for prefetch reads)

  // Workspace layout (~36 MB; >=71 MB proven available)
  float* ws = (float*)d_ws;
  size_t o = 0;
  __half* h1  = (__half*)(ws + o); o += (size_t)N * C1 / 2;   // layer-1 features fp16
  __half* x2h = (__half*)(ws + o); o += (size_t)N * C1 / 2;   // layer-2 input fp16
  float*  s1  = ws + o;            o += (size_t)N * HEADS1;
  float*  d1  = ws + o;            o += (size_t)N * HEADS1;
  __half* W1t = (__half*)(ws + o); o += 128 * 128 / 2;
  __half* W2t = (__half*)(ws + o); o += 64 * 128 / 2;
  int* deg        = (int*)(ws + o); o += N;
  int* cursor     = (int*)(ws + o); o += N;
  int* row_start  = (int*)(ws + o); o += N + 1;
  int* partial    = (int*)(ws + o); o += SB;
  int* src_sorted = (int*)(ws + o); o += EPAD;
  // layer-2 aliases into h1's region (h1 dead after layer1_agg)
  __half* h2 = h1;                                   // N*64 halves
  float*  s2 = (float*)h1 + (size_t)N * 32;          // N floats
  float*  d2 = s2 + N;                               // N floats

  const int EB = (E + 255) / 256;
  const int NB64 = (N + 63) / 64;
  const int tB = (128 * 128 + 64 * 128 + 255) / 256;
  const int AGGB = min((N + 3) / 4, 2048);   // persistent: 2048 blocks = 32 waves/CU

  hipMemsetAsync(deg, 0, (size_t)N * 4, stream);
  hipMemsetAsync(src_sorted, 0, (size_t)EPAD * 4, stream);   // pad slots -> node 0

  prep_kernel<<<tB + EB, 256, 0, stream>>>(W1, W1t, W2, W2t, dst, deg, tB, E);
  scan1_kernel<<<SB, SB, 0, stream>>>(deg, partial, cursor, N);
  scan3_kernel<<<SB, SB, 0, stream>>>(deg, partial, row_start, N);
  fill_kernel<<<EB, 256, 0, stream>>>(src, dst, row_start, cursor, src_sorted, E);

  // Layer 1
  gemm1_mfma<<<NB64, 256, 0, stream>>>(x, W1t, a_src1, a_dst1, h1, s1, d1, N);
  layer1_agg<<<AGGB, 256, 0, stream>>>(row_start, deg, src_sorted, s1, d1, h1, b1, x2h, N);

  // Layer 2
  gemm2_mfma<<<NB64, 256, 0, stream>>>(x2h, W2t, a_src2, a_dst2, h2, s2, d2, N);
  layer2_agg<<<AGGB, 256, 0, stream>>>(row_start, deg, src_sorted, s2, d2, h2, b2, out, N);
}

// Round 16
// 223.312 us; speedup vs baseline: 1.0114x; 1.0114x over previous
//
#include <hip/hip_runtime.h>
#include <hip/hip_fp16.h>

#define INCH   128
#define HEADS1 8
#define HID1   16
#define C1     128   // HEADS1*HID1
#define C2     64
#define NEG_SLOPE 0.2f
#define SB     256   // scan blocks / threads

using f16x8 = __attribute__((ext_vector_type(8))) _Float16;
using f32x4 = __attribute__((ext_vector_type(4))) float;

__device__ __forceinline__ float lrelu(float v) { return v >= 0.f ? v : NEG_SLOPE * v; }
// byte-offset swizzle within a 256B LDS row (rows are 128 fp16)
__device__ __forceinline__ int swzA(int row, int byteInRow) {
  return (row << 8) | (byteInRow ^ ((row & 15) << 4));
}

// ---------------- fused prep: x->fp16, W1/W2 transpose->fp16, dst histogram ----------------

__global__ void prep_kernel(const float* __restrict__ x, __half* __restrict__ xh,
                            const float* __restrict__ W1, __half* __restrict__ W1t,
                            const float* __restrict__ W2, __half* __restrict__ W2t,
                            const int* __restrict__ dst, int* __restrict__ deg,
                            int cvtB, int tB, int total8, int E) {
  const int b = blockIdx.x, t = threadIdx.x;
  if (b < cvtB) {
    int i = b * 256 + t;
    if (i >= total8) return;
    const float4* p = (const float4*)x + (size_t)i * 2;
    float4 v0 = p[0], v1 = p[1];
    __half2 ha = __floats2half2_rn(v0.x, v0.y);
    __half2 hb = __floats2half2_rn(v0.z, v0.w);
    __half2 hc = __floats2half2_rn(v1.x, v1.y);
    __half2 hd = __floats2half2_rn(v1.z, v1.w);
    uint4 w = { *(unsigned*)&ha, *(unsigned*)&hb, *(unsigned*)&hc, *(unsigned*)&hd };
    ((uint4*)xh)[i] = w;
  } else if (b < cvtB + tB) {
    int id = (b - cvtB) * 256 + t;
    if (id < 128 * 128) {
      int col = id >> 7, k = id & 127;
      W1t[id] = __float2half(W1[k * 128 + col]);
    } else if (id < 128 * 128 + 64 * 128) {
      int idx = id - 128 * 128;
      int col = idx >> 7, k = idx & 127;
      W2t[idx] = __float2half(W2[k * 64 + col]);
    }
  } else {
    int e = (b - cvtB - tB) * 256 + t;
    if (e < E) atomicAdd(&deg[dst[e]], 1);
  }
}

// ---------------- CSR build (by destination) ----------------

__global__ void scan1_kernel(const int* __restrict__ deg, int* __restrict__ partial, int N) {
  __shared__ int sh[SB];
  const int b = blockIdx.x, t = threadIdx.x;
  const int chunk = (N + SB - 1) / SB;
  const int lo = b * chunk, hi = min(lo + chunk, N);
  int s = 0;
  for (int i = lo + t; i < hi; i += SB) s += deg[i];
  sh[t] = s;
  __syncthreads();
  for (int off = SB / 2; off; off >>= 1) {
    if (t < off) sh[t] += sh[t + off];
    __syncthreads();
  }
  if (t == 0) partial[b] = sh[0];
}

// stage 2+3 fused: each block locally scans the 256 partials, then scans its chunk.
__global__ void scan3_kernel(const int* __restrict__ deg, const int* __restrict__ partial,
                             int* __restrict__ row_start, int N) {
  __shared__ int pref[SB];
  __shared__ int sh[SB];
  const int b = blockIdx.x, t = threadIdx.x;
  int pv = partial[t];
  pref[t] = pv;
  __syncthreads();
  for (int off = 1; off < SB; off <<= 1) {
    int u = (t >= off) ? pref[t - off] : 0;
    __syncthreads();
    pref[t] += u;
    __syncthreads();
  }
  const int chunk = (N + SB - 1) / SB;
  const int lo = b * chunk, hi = min(lo + chunk, N);
  int run = (b == 0) ? 0 : pref[b - 1];
  for (int base = lo; base < hi; base += SB) {
    int i = base + t;
    int v = (i < hi) ? deg[i] : 0;
    sh[t] = v;
    __syncthreads();
    for (int off = 1; off < SB; off <<= 1) {
      int u = (t >= off) ? sh[t - off] : 0;
      __syncthreads();
      sh[t] += u;
      __syncthreads();
    }
    if (i < hi) row_start[i] = run + sh[t] - v;
    run += sh[SB - 1];
    __syncthreads();
  }
  if (b == SB - 1 && t == 0) row_start[N] = run;
}

__global__ void fill_kernel(const int* __restrict__ src, const int* __restrict__ dst,
                            const int* __restrict__ row_start, int* __restrict__ cursor,
                            int* __restrict__ src_sorted, int E) {
  int e = blockIdx.x * blockDim.x + threadIdx.x;
  if (e >= E) return;
  int d = dst[e];
  int slot = row_start[d] + atomicAdd(&cursor[d], 1);
  src_sorted[slot] = src[e];
}

// ---------------- MFMA GEMMs ----------------
// gemm1: [M x 128] x [128 x 128]; 256 thr = 4 waves; block does 64 rows x 128 cols.
__global__ __launch_bounds__(256) void gemm1_mfma(
    const __half* __restrict__ xh, const __half* __restrict__ W1t,
    const float* __restrict__ a_src, const float* __restrict__ a_dst,
    __half* __restrict__ h1, float* __restrict__ s1, float* __restrict__ d1, int M) {
  __shared__ unsigned char As[16384];   // 64 x 128 fp16, swizzled
  __shared__ unsigned char Bs[32768];   // 128 x 128 fp16 (col-major W1), swizzled
  const int t = threadIdx.x;
  const int m0 = blockIdx.x * 64;
  for (int c = t; c < 1024; c += 256) {
    int row = c >> 4, seg = c & 15;
    int gr = m0 + row;
    uint4 v = make_uint4(0, 0, 0, 0);
    if (gr < M) v = ((const uint4*)xh)[(unsigned)(gr << 4) + seg];
    *(uint4*)(As + swzA(row, seg << 4)) = v;
  }
  for (int c = t; c < 2048; c += 256) {
    int row = c >> 4, seg = c & 15;
    uint4 v = ((const uint4*)W1t)[(row << 4) + seg];
    *(uint4*)(Bs + swzA(row, seg << 4)) = v;
  }
  __syncthreads();
  const int l = t & 63, wid = t >> 6;
  const int c16 = l & 15;
  const int kOff = (l >> 4) << 4;
  const int rA = (wid << 4) | c16;
  f16x8 a[4];
#pragma unroll
  for (int kb = 0; kb < 4; ++kb)
    a[kb] = *(const f16x8*)(As + swzA(rA, (kb << 6) + kOff));
#pragma unroll
  for (int ct = 0; ct < 8; ++ct) {        // ct == head (HID1 == 16)
    const int rB = (ct << 4) | c16;
    f32x4 acc = {0.f, 0.f, 0.f, 0.f};
#pragma unroll
    for (int kb = 0; kb < 4; ++kb) {
      f16x8 b = *(const f16x8*)(Bs + swzA(rB, (kb << 6) + kOff));
      acc = __builtin_amdgcn_mfma_f32_16x16x32_f16(a[kb], b, acc, 0, 0, 0);
    }
    const int colg = (ct << 4) + c16;
    const float asv = a_src[colg], adv = a_dst[colg];
#pragma unroll
    for (int i = 0; i < 4; ++i) {
      const int n = m0 + (wid << 4) + ((l >> 4) << 2) + i;
      float v = acc[i];
      float sv = v * asv, dv = v * adv;
      sv += __shfl_xor(sv, 1); sv += __shfl_xor(sv, 2);
      sv += __shfl_xor(sv, 4); sv += __shfl_xor(sv, 8);
      dv += __shfl_xor(dv, 1); dv += __shfl_xor(dv, 2);
      dv += __shfl_xor(dv, 4); dv += __shfl_xor(dv, 8);
      if (n < M) {
        h1[(unsigned)(n << 7) + colg] = __float2half(v);
        if (c16 == 0) { s1[n * HEADS1 + ct] = sv; d1[n * HEADS1 + ct] = dv; }
      }
    }
  }
}

// gemm2: [M x 128] x [128 x 64]
__global__ __launch_bounds__(256) void gemm2_mfma(
    const __half* __restrict__ x2h, const __half* __restrict__ W2t,
    const float* __restrict__ a_src, const float* __restrict__ a_dst,
    __half* __restrict__ h2, float* __restrict__ s2, float* __restrict__ d2, int M) {
  __shared__ unsigned char As[16384];   // 64 x 128 fp16
  __shared__ unsigned char Bs[16384];   // 64 x 128 fp16 (col-major W2)
  const int t = threadIdx.x;
  const int m0 = blockIdx.x * 64;
  for (int c = t; c < 1024; c += 256) {
    int row = c >> 4, seg = c & 15;
    int gr = m0 + row;
    uint4 v = make_uint4(0, 0, 0, 0);
    if (gr < M) v = ((const uint4*)x2h)[(unsigned)(gr << 4) + seg];
    *(uint4*)(As + swzA(row, seg << 4)) = v;
  }
  for (int c = t; c < 1024; c += 256) {
    int row = c >> 4, seg = c & 15;
    uint4 v = ((const uint4*)W2t)[(row << 4) + seg];
    *(uint4*)(Bs + swzA(row, seg << 4)) = v;
  }
  __syncthreads();
  const int l = t & 63, wid = t >> 6;
  const int c16 = l & 15;
  const int kOff = (l >> 4) << 4;
  const int rA = (wid << 4) | c16;
  f16x8 a[4];
#pragma unroll
  for (int kb = 0; kb < 4; ++kb)
    a[kb] = *(const f16x8*)(As + swzA(rA, (kb << 6) + kOff));
  float svp[4] = {0.f, 0.f, 0.f, 0.f};
  float dvp[4] = {0.f, 0.f, 0.f, 0.f};
#pragma unroll
  for (int ct = 0; ct < 4; ++ct) {
    const int rB = (ct << 4) | c16;
    f32x4 acc = {0.f, 0.f, 0.f, 0.f};
#pragma unroll
    for (int kb = 0; kb < 4; ++kb) {
      f16x8 b = *(const f16x8*)(Bs + swzA(rB, (kb << 6) + kOff));
      acc = __builtin_amdgcn_mfma_f32_16x16x32_f16(a[kb], b, acc, 0, 0, 0);
    }
    const int colg = (ct << 4) + c16;
    const float asv = a_src[colg], adv = a_dst[colg];
#pragma unroll
    for (int i = 0; i < 4; ++i) {
      const int n = m0 + (wid << 4) + ((l >> 4) << 2) + i;
      float v = acc[i];
      svp[i] += v * asv;
      dvp[i] += v * adv;
      if (n < M) h2[(unsigned)(n << 6) + colg] = __float2half(v);
    }
  }
#pragma unroll
  for (int i = 0; i < 4; ++i) {
    float sv = svp[i], dv = dvp[i];
    sv += __shfl_xor(sv, 1); sv += __shfl_xor(sv, 2);
    sv += __shfl_xor(sv, 4); sv += __shfl_xor(sv, 8);
    dv += __shfl_xor(dv, 1); dv += __shfl_xor(dv, 2);
    dv += __shfl_xor(dv, 4); dv += __shfl_xor(dv, 8);
    const int n = m0 + (wid << 4) + ((l >> 4) << 2) + i;
    if (c16 == 0 && n < M) { s2[n] = sv; d2[n] = dv; }
  }
}

// ---------------- Fused softmax + wide aggregation (no max pass; grid-stride;
//                  clamped in-segment row-prefetch, 16 always + 16 when deg>16) ----
// Softmax is shift-invariant; logits lrelu(s+d) are O(1..8) for this model's
// 1/sqrt(fan_in)-scaled weights -> exp() fp32-safe without max subtraction.
// Persistent launch: 2048 blocks x 4 waves = 32 waves/CU.
__global__ __launch_bounds__(256) void layer1_agg(
    const int* __restrict__ row_start, const int* __restrict__ src_sorted,
    const float* __restrict__ s1, const float* __restrict__ d1,
    const __half* __restrict__ h1, const float* __restrict__ b1,
    __half* __restrict__ x2h, int N) {
  __shared__ float wlds[4][64][8];   // [wave][slot][head]
  const int wv = threadIdx.x >> 6;
  const int lane = threadIdx.x & 63;
  const int le = lane >> 3, h = lane & 7;     // phase 1
  const int es = lane >> 4, cl = lane & 15;   // phase 2
  const int hh = cl >> 1;
  const uint4* __restrict__ h1v = (const uint4*)h1;
  const int waveId = blockIdx.x * 4 + wv;
  const int stride = gridDim.x * 4;
  for (int n = waveId; n < N; n += stride) {
    const int lo = row_start[n], hi = row_start[n + 1];
    const float dv = d1[n * HEADS1 + h];
    float z = 0.f;
    float acc[8] = {0.f, 0.f, 0.f, 0.f, 0.f, 0.f, 0.f, 0.f};
    for (int base = lo; base < hi; base += 64) {
      const int cnt = min(64, hi - base);
      const int c1 = cnt - 1;
      // ---- phase 0: issue clamped in-segment row gathers for slots 0..15,
      //      plus 16..31 when this chunk has more than 16 edges (wave-uniform).
      const int ps0 = src_sorted[base + min(es, c1)];
      const int ps1 = src_sorted[base + min(4 + es, c1)];
      const int ps2 = src_sorted[base + min(8 + es, c1)];
      const int ps3 = src_sorted[base + min(12 + es, c1)];
      const uint4 pf0 = h1v[(unsigned)(ps0 << 4) + cl];
      const uint4 pf1 = h1v[(unsigned)(ps1 << 4) + cl];
      const uint4 pf2 = h1v[(unsigned)(ps2 << 4) + cl];
      const uint4 pf3 = h1v[(unsigned)(ps3 << 4) + cl];
      uint4 pf4, pf5, pf6, pf7;
      const bool big = (cnt > 16);
      if (big) {
        const int ps4 = src_sorted[base + min(16 + es, c1)];
        const int ps5 = src_sorted[base + min(20 + es, c1)];
        const int ps6 = src_sorted[base + min(24 + es, c1)];
        const int ps7 = src_sorted[base + min(28 + es, c1)];
        pf4 = h1v[(unsigned)(ps4 << 4) + cl];
        pf5 = h1v[(unsigned)(ps5 << 4) + cl];
        pf6 = h1v[(unsigned)(ps6 << 4) + cl];
        pf7 = h1v[(unsigned)(ps7 << 4) + cl];
      }
      // ---- phase 1: w = exp(logit) -> LDS; only the slots phase 2 will read
      const int rmax = (cnt + 7) >> 3;   // wave-uniform
      for (int r = 0; r < rmax; ++r) {
        const int j = (r << 3) + le;
        float w = 0.f;
        if (j < cnt) w = __expf(lrelu(s1[src_sorted[base + j] * HEADS1 + h] + dv));
        wlds[wv][j][h] = w;
        z += w;
      }
      // ---- phase 2a: consume prefetched rows (slots 0..15)
      {
        const float wA = wlds[wv][es][hh];
        const float wB = wlds[wv][4 + es][hh];
        const __half2* pA = (const __half2*)&pf0;
        const __half2* pB = (const __half2*)&pf1;
#pragma unroll
        for (int k = 0; k < 4; ++k) {
          float2 a2 = __half22float2(pA[k]);
          float2 b2v = __half22float2(pB[k]);
          acc[2 * k]     += wA * a2.x + wB * b2v.x;
          acc[2 * k + 1] += wA * a2.y + wB * b2v.y;
        }
      }
      if (cnt > 8) {
        const float wA = wlds[wv][8 + es][hh];
        const float wB = wlds[wv][12 + es][hh];
        const __half2* pA = (const __half2*)&pf2;
        const __half2* pB = (const __half2*)&pf3;
#pragma unroll
        for (int k = 0; k < 4; ++k) {
          float2 a2 = __half22float2(pA[k]);
          float2 b2v = __half22float2(pB[k]);
          acc[2 * k]     += wA * a2.x + wB * b2v.x;
          acc[2 * k + 1] += wA * a2.y + wB * b2v.y;
        }
      }
      // ---- phase 2a': consume prefetched rows (slots 16..31), wave-uniform guards
      if (big) {
        const float wA = wlds[wv][16 + es][hh];
        const float wB = wlds[wv][20 + es][hh];
        const __half2* pA = (const __half2*)&pf4;
        const __half2* pB = (const __half2*)&pf5;
#pragma unroll
        for (int k = 0; k < 4; ++k) {
          float2 a2 = __half22float2(pA[k]);
          float2 b2v = __half22float2(pB[k]);
          acc[2 * k]     += wA * a2.x + wB * b2v.x;
          acc[2 * k + 1] += wA * a2.y + wB * b2v.y;
        }
      }
      if (cnt > 24) {
        const float wA = wlds[wv][24 + es][hh];
        const float wB = wlds[wv][28 + es][hh];
        const __half2* pA = (const __half2*)&pf6;
        const __half2* pB = (const __half2*)&pf7;
#pragma unroll
        for (int k = 0; k < 4; ++k) {
          float2 a2 = __half22float2(pA[k]);
          float2 b2v = __half22float2(pB[k]);
          acc[2 * k]     += wA * a2.x + wB * b2v.x;
          acc[2 * k + 1] += wA * a2.y + wB * b2v.y;
        }
      }
      // ---- phase 2b: remaining slots (deg > 32 within this chunk; rare)
      for (int i = 32; i < cnt; i += 8) {
        const int jA = i + es, jB = i + 4 + es;
        const float wA = wlds[wv][jA][hh];
        const float wB = wlds[wv][jB][hh];
        const int sA = src_sorted[base + min(jA, c1)];
        const int sB = src_sorted[base + min(jB, c1)];
        const uint4 fA = h1v[(unsigned)(sA << 4) + cl];
        const uint4 fB = h1v[(unsigned)(sB << 4) + cl];
        const __half2* pA = (const __half2*)&fA;
        const __half2* pB = (const __half2*)&fB;
#pragma unroll
        for (int k = 0; k < 4; ++k) {
          float2 a2 = __half22float2(pA[k]);
          float2 b2v = __half22float2(pB[k]);
          acc[2 * k]     += wA * a2.x + wB * b2v.x;
          acc[2 * k + 1] += wA * a2.y + wB * b2v.y;
        }
      }
    }
    // finalize: z per (le,h) partial; reduce over le (lanes with same h)
    z += __shfl_xor(z, 8); z += __shfl_xor(z, 16); z += __shfl_xor(z, 32);
    const float zsel = __shfl(z, hh);   // lane hh holds head hh's total
#pragma unroll
    for (int k = 0; k < 8; ++k) {
      acc[k] += __shfl_xor(acc[k], 16);
      acc[k] += __shfl_xor(acc[k], 32);
    }
    if (es == 0) {
      const float zinv = 1.f / (zsel + 1e-16f);
      __half2 o[4];
#pragma unroll
      for (int k = 0; k < 4; ++k) {
        float ox = acc[2 * k] * zinv + b1[(cl << 3) + 2 * k];
        float oy = acc[2 * k + 1] * zinv + b1[(cl << 3) + 2 * k + 1];
        ox = ox > 0.f ? ox : expm1f(ox);
        oy = oy > 0.f ? oy : expm1f(oy);
        o[k] = __floats2half2_rn(ox, oy);
      }
      ((uint4*)x2h)[(unsigned)(n << 4) + cl] = *(const uint4*)o;
    }
  }
}

// layer2: one wave per node (grid-stride), 1 head; clamped prefetch of 32 slots.
// Phase1: slot=lane (w in register, shared by shuffle). Phase2: es=lane>>3, cl=lane&7.
__global__ __launch_bounds__(256) void layer2_agg(
    const int* __restrict__ row_start, const int* __restrict__ src_sorted,
    const float* __restrict__ s2, const float* __restrict__ d2,
    const __half* __restrict__ h2, const float* __restrict__ b2,
    float* __restrict__ out, int N) {
  const int wv = threadIdx.x >> 6;
  const int lane = threadIdx.x & 63;
  const int es = lane >> 3, cl = lane & 7;
  const uint4* __restrict__ h2v = (const uint4*)h2;
  const int waveId = blockIdx.x * 4 + wv;
  const int stride = gridDim.x * 4;
  for (int n = waveId; n < N; n += stride) {
    const int lo = row_start[n], hi = row_start[n + 1];
    const float dv = d2[n];
    float z = 0.f;
    float acc[8] = {0.f, 0.f, 0.f, 0.f, 0.f, 0.f, 0.f, 0.f};
    for (int base = lo; base < hi; base += 64) {
      const int cnt = min(64, hi - base);
      const int c1 = cnt - 1;
      // ---- phase 0: clamped in-segment prefetch for the first 32 slots
      const int ps0 = src_sorted[base + min(es, c1)];
      const int ps1 = src_sorted[base + min(8 + es, c1)];
      const int ps2 = src_sorted[base + min(16 + es, c1)];
      const int ps3 = src_sorted[base + min(24 + es, c1)];
      const uint4 pf0 = h2v[(unsigned)(ps0 << 3) + cl];
      const uint4 pf1 = h2v[(unsigned)(ps1 << 3) + cl];
      const uint4 pf2 = h2v[(unsigned)(ps2 << 3) + cl];
      const uint4 pf3 = h2v[(unsigned)(ps3 << 3) + cl];
      // ---- phase 1
      float w = 0.f;
      if (lane < cnt) w = __expf(lrelu(s2[src_sorted[base + lane]] + dv));
      z += w;
      // ---- phase 2a: consume prefetched (slots 0..31)
      {
        const float wA = __shfl(w, es);
        const float wB = __shfl(w, 8 + es);
        const __half2* pA = (const __half2*)&pf0;
        const __half2* pB = (const __half2*)&pf1;
#pragma unroll
        for (int k = 0; k < 4; ++k) {
          float2 a2 = __half22float2(pA[k]);
          float2 b2v = __half22float2(pB[k]);
          acc[2 * k]     += wA * a2.x + wB * b2v.x;
          acc[2 * k + 1] += wA * a2.y + wB * b2v.y;
        }
      }
      if (cnt > 16) {
        const float wA = __shfl(w, 16 + es);
        const float wB = __shfl(w, 24 + es);
        const __half2* pA = (const __half2*)&pf2;
        const __half2* pB = (const __half2*)&pf3;
#pragma unroll
        for (int k = 0; k < 4; ++k) {
          float2 a2 = __half22float2(pA[k]);
          float2 b2v = __half22float2(pB[k]);
          acc[2 * k]     += wA * a2.x + wB * b2v.x;
          acc[2 * k + 1] += wA * a2.y + wB * b2v.y;
        }
      }
      // ---- phase 2b: remaining edges
      for (int i = 32; i < cnt; i += 16) {   // wave-uniform
        const int jA = i + es, jB = i + 8 + es;
        const float wA = __shfl(w, jA);
        const float wB = __shfl(w, jB);
        const int sA = src_sorted[base + min(jA, c1)];
        const int sB = src_sorted[base + min(jB, c1)];
        const uint4 fA = h2v[(unsigned)(sA << 3) + cl];
        const uint4 fB = h2v[(unsigned)(sB << 3) + cl];
        const __half2* pA = (const __half2*)&fA;
        const __half2* pB = (const __half2*)&fB;
#pragma unroll
        for (int k = 0; k < 4; ++k) {
          float2 a2 = __half22float2(pA[k]);
          float2 b2v = __half22float2(pB[k]);
          acc[2 * k]     += wA * a2.x + wB * b2v.x;
          acc[2 * k + 1] += wA * a2.y + wB * b2v.y;
        }
      }
    }
#pragma unroll
    for (int off = 1; off < 64; off <<= 1) z += __shfl_xor(z, off);
#pragma unroll
    for (int k = 0; k < 8; ++k) {
      acc[k] += __shfl_xor(acc[k], 8);
      acc[k] += __shfl_xor(acc[k], 16);
      acc[k] += __shfl_xor(acc[k], 32);
    }
    if (es == 0) {
      const float zinv = 1.f / (z + 1e-16f);
      float4 o0, o1;
      o0.x = acc[0] * zinv + b2[(cl << 3) + 0];
      o0.y = acc[1] * zinv + b2[(cl << 3) + 1];
      o0.z = acc[2] * zinv + b2[(cl << 3) + 2];
      o0.w = acc[3] * zinv + b2[(cl << 3) + 3];
      o1.x = acc[4] * zinv + b2[(cl << 3) + 4];
      o1.y = acc[5] * zinv + b2[(cl << 3) + 5];
      o1.z = acc[6] * zinv + b2[(cl << 3) + 6];
      o1.w = acc[7] * zinv + b2[(cl << 3) + 7];
      float4* po = (float4*)&out[(unsigned)(n << 6) + (cl << 3)];
      po[0] = o0;
      po[1] = o1;
    }
  }
}

extern "C" void kernel_launch(void* const* d_in, const int* in_sizes, int n_in,
                              void* d_out, int out_size, void* d_ws, size_t ws_size,
                              hipStream_t stream) {
  const float* x      = (const float*)d_in[0];
  const int*   ei     = (const int*)d_in[1];
  const float* W1     = (const float*)d_in[2];
  const float* a_src1 = (const float*)d_in[3];
  const float* a_dst1 = (const float*)d_in[4];
  const float* b1     = (const float*)d_in[5];
  const float* W2     = (const float*)d_in[6];
  const float* a_src2 = (const float*)d_in[7];
  const float* a_dst2 = (const float*)d_in[8];
  const float* b2     = (const float*)d_in[9];
  float* out = (float*)d_out;

  const int N = in_sizes[0] / INCH;
  const int E = in_sizes[1] / 2;
  const int* src = ei;
  const int* dst = ei + E;

  // Workspace layout (~46 MB; >=71 MB proven available)
  float* ws = (float*)d_ws;
  size_t o = 0;
  __half* xh  = (__half*)(ws + o); o += (size_t)N * C1 / 2;   // x fp16
  __half* h1  = (__half*)(ws + o); o += (size_t)N * C1 / 2;   // layer-1 features fp16
  __half* x2h = (__half*)(ws + o); o += (size_t)N * C1 / 2;   // layer-2 input fp16
  float*  s1  = ws + o;            o += (size_t)N * HEADS1;
  float*  d1  = ws + o;            o += (size_t)N * HEADS1;
  __half* W1t = (__half*)(ws + o); o += 128 * 128 / 2;
  __half* W2t = (__half*)(ws + o); o += 64 * 128 / 2;
  int* deg        = (int*)(ws + o); o += N;
  int* cursor     = (int*)(ws + o); o += N;
  int* row_start  = (int*)(ws + o); o += N + 1;
  int* partial    = (int*)(ws + o); o += SB;
  int* src_sorted = (int*)(ws + o); o += E;
  // layer-2 aliases into h1's region (h1 dead after layer1_agg)
  __half* h2 = h1;                                   // N*64 halves
  float*  s2 = (float*)h1 + (size_t)N * 32;          // N floats
  float*  d2 = s2 + N;                               // N floats

  const int EB = (E + 255) / 256;
  const int NB64 = (N + 63) / 64;
  const int total8 = N * C1 / 8;
  const int cvtB = (total8 + 255) / 256;
  const int tB = (128 * 128 + 64 * 128 + 255) / 256;
  const int histB = EB;
  const int AGGB = min((N + 3) / 4, 2048);   // persistent: 2048 blocks = 32 waves/CU

  hipMemsetAsync(deg, 0, (size_t)N * 4, stream);
  hipMemsetAsync(cursor, 0, (size_t)N * 4, stream);

  prep_kernel<<<cvtB + tB + histB, 256, 0, stream>>>(x, xh, W1, W1t, W2, W2t, dst, deg,
                                                     cvtB, tB, total8, E);
  scan1_kernel<<<SB, SB, 0, stream>>>(deg, partial, N);
  scan3_kernel<<<SB, SB, 0, stream>>>(deg, partial, row_start, N);
  fill_kernel<<<EB, 256, 0, stream>>>(src, dst, row_start, cursor, src_sorted, E);

  // Layer 1
  gemm1_mfma<<<NB64, 256, 0, stream>>>(xh, W1t, a_src1, a_dst1, h1, s1, d1, N);
  layer1_agg<<<AGGB, 256, 0, stream>>>(row_start, src_sorted, s1, d1, h1, b1, x2h, N);

  // Layer 2
  gemm2_mfma<<<NB64, 256, 0, stream>>>(x2h, W2t, a_src2, a_dst2, h2, s2, d2, N);
  layer2_agg<<<AGGB, 256, 0, stream>>>(row_start, src_sorted, s2, d2, h2, b2, out, N);
}

// Round 17
// 197.291 us; speedup vs baseline: 1.1448x; 1.1319x over previous
//
#include <hip/hip_runtime.h>
#include <hip/hip_fp16.h>

#define INCH   128
#define HEADS1 8
#define HID1   16
#define C1     128   // HEADS1*HID1
#define C2     64
#define NEG_SLOPE 0.2f
#define SB     256   // scan blocks / threads

using f16x8 = __attribute__((ext_vector_type(8))) _Float16;
using f32x4 = __attribute__((ext_vector_type(4))) float;

__device__ __forceinline__ float lrelu(float v) { return v >= 0.f ? v : NEG_SLOPE * v; }
// byte-offset swizzle within a 256B LDS row (rows are 128 fp16)
__device__ __forceinline__ int swzA(int row, int byteInRow) {
  return (row << 8) | (byteInRow ^ ((row & 15) << 4));
}

// ---------------- fused prep: x->fp16, W1/W2 transpose->fp16, dst histogram ----------------

__global__ void prep_kernel(const float* __restrict__ x, __half* __restrict__ xh,
                            const float* __restrict__ W1, __half* __restrict__ W1t,
                            const float* __restrict__ W2, __half* __restrict__ W2t,
                            const int* __restrict__ dst, int* __restrict__ deg,
                            int cvtB, int tB, int total8, int E) {
  const int b = blockIdx.x, t = threadIdx.x;
  if (b < cvtB) {
    int i = b * 256 + t;
    if (i >= total8) return;
    const float4* p = (const float4*)x + (size_t)i * 2;
    float4 v0 = p[0], v1 = p[1];
    __half2 ha = __floats2half2_rn(v0.x, v0.y);
    __half2 hb = __floats2half2_rn(v0.z, v0.w);
    __half2 hc = __floats2half2_rn(v1.x, v1.y);
    __half2 hd = __floats2half2_rn(v1.z, v1.w);
    uint4 w = { *(unsigned*)&ha, *(unsigned*)&hb, *(unsigned*)&hc, *(unsigned*)&hd };
    ((uint4*)xh)[i] = w;
  } else if (b < cvtB + tB) {
    int id = (b - cvtB) * 256 + t;
    if (id < 128 * 128) {
      int col = id >> 7, k = id & 127;
      W1t[id] = __float2half(W1[k * 128 + col]);
    } else if (id < 128 * 128 + 64 * 128) {
      int idx = id - 128 * 128;
      int col = idx >> 7, k = idx & 127;
      W2t[idx] = __float2half(W2[k * 64 + col]);
    }
  } else {
    int e = (b - cvtB - tB) * 256 + t;
    if (e < E) atomicAdd(&deg[dst[e]], 1);
  }
}

// ---------------- CSR build (by destination) ----------------

__global__ void scan1_kernel(const int* __restrict__ deg, int* __restrict__ partial, int N) {
  __shared__ int sh[SB];
  const int b = blockIdx.x, t = threadIdx.x;
  const int chunk = (N + SB - 1) / SB;
  const int lo = b * chunk, hi = min(lo + chunk, N);
  int s = 0;
  for (int i = lo + t; i < hi; i += SB) s += deg[i];
  sh[t] = s;
  __syncthreads();
  for (int off = SB / 2; off; off >>= 1) {
    if (t < off) sh[t] += sh[t + off];
    __syncthreads();
  }
  if (t == 0) partial[b] = sh[0];
}

// stage 2+3 fused: each block locally scans the 256 partials, then scans its chunk.
__global__ void scan3_kernel(const int* __restrict__ deg, const int* __restrict__ partial,
                             int* __restrict__ row_start, int N) {
  __shared__ int pref[SB];
  __shared__ int sh[SB];
  const int b = blockIdx.x, t = threadIdx.x;
  int pv = partial[t];
  pref[t] = pv;
  __syncthreads();
  for (int off = 1; off < SB; off <<= 1) {
    int u = (t >= off) ? pref[t - off] : 0;
    __syncthreads();
    pref[t] += u;
    __syncthreads();
  }
  const int chunk = (N + SB - 1) / SB;
  const int lo = b * chunk, hi = min(lo + chunk, N);
  int run = (b == 0) ? 0 : pref[b - 1];
  for (int base = lo; base < hi; base += SB) {
    int i = base + t;
    int v = (i < hi) ? deg[i] : 0;
    sh[t] = v;
    __syncthreads();
    for (int off = 1; off < SB; off <<= 1) {
      int u = (t >= off) ? sh[t - off] : 0;
      __syncthreads();
      sh[t] += u;
      __syncthreads();
    }
    if (i < hi) row_start[i] = run + sh[t] - v;
    run += sh[SB - 1];
    __syncthreads();
  }
  if (b == SB - 1 && t == 0) row_start[N] = run;
}

__global__ void fill_kernel(const int* __restrict__ src, const int* __restrict__ dst,
                            const int* __restrict__ row_start, int* __restrict__ cursor,
                            int* __restrict__ src_sorted, int E) {
  int e = blockIdx.x * blockDim.x + threadIdx.x;
  if (e >= E) return;
  int d = dst[e];
  int slot = row_start[d] + atomicAdd(&cursor[d], 1);
  src_sorted[slot] = src[e];
}

// ---------------- MFMA GEMMs ----------------
// gemm1: [M x 128] x [128 x 128]; 256 thr = 4 waves; block does 64 rows x 128 cols.
__global__ __launch_bounds__(256) void gemm1_mfma(
    const __half* __restrict__ xh, const __half* __restrict__ W1t,
    const float* __restrict__ a_src, const float* __restrict__ a_dst,
    __half* __restrict__ h1, float* __restrict__ s1, float* __restrict__ d1, int M) {
  __shared__ unsigned char As[16384];   // 64 x 128 fp16, swizzled
  __shared__ unsigned char Bs[32768];   // 128 x 128 fp16 (col-major W1), swizzled
  const int t = threadIdx.x;
  const int m0 = blockIdx.x * 64;
  for (int c = t; c < 1024; c += 256) {
    int row = c >> 4, seg = c & 15;
    int gr = m0 + row;
    uint4 v = make_uint4(0, 0, 0, 0);
    if (gr < M) v = ((const uint4*)xh)[(unsigned)(gr << 4) + seg];
    *(uint4*)(As + swzA(row, seg << 4)) = v;
  }
  for (int c = t; c < 2048; c += 256) {
    int row = c >> 4, seg = c & 15;
    uint4 v = ((const uint4*)W1t)[(row << 4) + seg];
    *(uint4*)(Bs + swzA(row, seg << 4)) = v;
  }
  __syncthreads();
  const int l = t & 63, wid = t >> 6;
  const int c16 = l & 15;
  const int kOff = (l >> 4) << 4;
  const int rA = (wid << 4) | c16;
  f16x8 a[4];
#pragma unroll
  for (int kb = 0; kb < 4; ++kb)
    a[kb] = *(const f16x8*)(As + swzA(rA, (kb << 6) + kOff));
#pragma unroll
  for (int ct = 0; ct < 8; ++ct) {        // ct == head (HID1 == 16)
    const int rB = (ct << 4) | c16;
    f32x4 acc = {0.f, 0.f, 0.f, 0.f};
#pragma unroll
    for (int kb = 0; kb < 4; ++kb) {
      f16x8 b = *(const f16x8*)(Bs + swzA(rB, (kb << 6) + kOff));
      acc = __builtin_amdgcn_mfma_f32_16x16x32_f16(a[kb], b, acc, 0, 0, 0);
    }
    const int colg = (ct << 4) + c16;
    const float asv = a_src[colg], adv = a_dst[colg];
#pragma unroll
    for (int i = 0; i < 4; ++i) {
      const int n = m0 + (wid << 4) + ((l >> 4) << 2) + i;
      float v = acc[i];
      float sv = v * asv, dv = v * adv;
      sv += __shfl_xor(sv, 1); sv += __shfl_xor(sv, 2);
      sv += __shfl_xor(sv, 4); sv += __shfl_xor(sv, 8);
      dv += __shfl_xor(dv, 1); dv += __shfl_xor(dv, 2);
      dv += __shfl_xor(dv, 4); dv += __shfl_xor(dv, 8);
      if (n < M) {
        h1[(unsigned)(n << 7) + colg] = __float2half(v);
        if (c16 == 0) { s1[n * HEADS1 + ct] = sv; d1[n * HEADS1 + ct] = dv; }
      }
    }
  }
}

// gemm2: [M x 128] x [128 x 64]
__global__ __launch_bounds__(256) void gemm2_mfma(
    const __half* __restrict__ x2h, const __half* __restrict__ W2t,
    const float* __restrict__ a_src, const float* __restrict__ a_dst,
    __half* __restrict__ h2, float* __restrict__ s2, float* __restrict__ d2, int M) {
  __shared__ unsigned char As[16384];   // 64 x 128 fp16
  __shared__ unsigned char Bs[16384];   // 64 x 128 fp16 (col-major W2)
  const int t = threadIdx.x;
  const int m0 = blockIdx.x * 64;
  for (int c = t; c < 1024; c += 256) {
    int row = c >> 4, seg = c & 15;
    int gr = m0 + row;
    uint4 v = make_uint4(0, 0, 0, 0);
    if (gr < M) v = ((const uint4*)x2h)[(unsigned)(gr << 4) + seg];
    *(uint4*)(As + swzA(row, seg << 4)) = v;
  }
  for (int c = t; c < 1024; c += 256) {
    int row = c >> 4, seg = c & 15;
    uint4 v = ((const uint4*)W2t)[(row << 4) + seg];
    *(uint4*)(Bs + swzA(row, seg << 4)) = v;
  }
  __syncthreads();
  const int l = t & 63, wid = t >> 6;
  const int c16 = l & 15;
  const int kOff = (l >> 4) << 4;
  const int rA = (wid << 4) | c16;
  f16x8 a[4];
#pragma unroll
  for (int kb = 0; kb < 4; ++kb)
    a[kb] = *(const f16x8*)(As + swzA(rA, (kb << 6) + kOff));
  float svp[4] = {0.f, 0.f, 0.f, 0.f};
  float dvp[4] = {0.f, 0.f, 0.f, 0.f};
#pragma unroll
  for (int ct = 0; ct < 4; ++ct) {
    const int rB = (ct << 4) | c16;
    f32x4 acc = {0.f, 0.f, 0.f, 0.f};
#pragma unroll
    for (int kb = 0; kb < 4; ++kb) {
      f16x8 b = *(const f16x8*)(Bs + swzA(rB, (kb << 6) + kOff));
      acc = __builtin_amdgcn_mfma_f32_16x16x32_f16(a[kb], b, acc, 0, 0, 0);
    }
    const int colg = (ct << 4) + c16;
    const float asv = a_src[colg], adv = a_dst[colg];
#pragma unroll
    for (int i = 0; i < 4; ++i) {
      const int n = m0 + (wid << 4) + ((l >> 4) << 2) + i;
      float v = acc[i];
      svp[i] += v * asv;
      dvp[i] += v * adv;
      if (n < M) h2[(unsigned)(n << 6) + colg] = __float2half(v);
    }
  }
#pragma unroll
  for (int i = 0; i < 4; ++i) {
    float sv = svp[i], dv = dvp[i];
    sv += __shfl_xor(sv, 1); sv += __shfl_xor(sv, 2);
    sv += __shfl_xor(sv, 4); sv += __shfl_xor(sv, 8);
    dv += __shfl_xor(dv, 1); dv += __shfl_xor(dv, 2);
    dv += __shfl_xor(dv, 4); dv += __shfl_xor(dv, 8);
    const int n = m0 + (wid << 4) + ((l >> 4) << 2) + i;
    if (c16 == 0 && n < M) { s2[n] = sv; d2[n] = dv; }
  }
}

// ---------------- Fused softmax + wide aggregation ----------------
// Key ordering fix vs prior rounds: s1 logit gathers are issued BEFORE the row
// gathers. vmcnt retirement is in-order, so waiting on the (older) s1 loads
// leaves the (younger) row loads in flight -> true overlap of row fetch with
// the exp/weight computation. Weights for the first 16 slots are exchanged by
// shuffle (slot j, head hh lives in lane ((j&7)<<3)|hh); LDS used only for the
// deg>16 tail. Softmax max-pass dropped (shift-invariant; logits O(1..8)).
// Persistent launch: 2048 blocks x 4 waves = 32 waves/CU.
__global__ __launch_bounds__(256) void layer1_agg(
    const int* __restrict__ row_start, const int* __restrict__ src_sorted,
    const float* __restrict__ s1, const float* __restrict__ d1,
    const __half* __restrict__ h1, const float* __restrict__ b1,
    __half* __restrict__ x2h, int N) {
  __shared__ float wlds[4][64][8];   // [wave][slot][head] (tail slots >=16 only)
  const int wv = threadIdx.x >> 6;
  const int lane = threadIdx.x & 63;
  const int le = lane >> 3, h = lane & 7;     // phase 1
  const int es = lane >> 4, cl = lane & 15;   // phase 2
  const int hh = cl >> 1;
  const uint4* __restrict__ h1v = (const uint4*)h1;
  const int waveId = blockIdx.x * 4 + wv;
  const int stride = gridDim.x * 4;
  for (int n = waveId; n < N; n += stride) {
    const int lo = row_start[n], hi = row_start[n + 1];
    const float dv = d1[n * HEADS1 + h];
    float z = 0.f;
    float acc[8] = {0.f, 0.f, 0.f, 0.f, 0.f, 0.f, 0.f, 0.f};
    for (int base = lo; base < hi; base += 64) {
      const int cnt = min(64, hi - base);
      const int c1 = cnt - 1;
      // ---- A: logit-input gathers for slots 0..15 (issued FIRST = oldest)
      const int j0 = le, j1 = 8 + le;
      const int sj0 = src_sorted[base + min(j0, c1)];
      const int sj1 = src_sorted[base + min(j1, c1)];
      const float sv0 = s1[sj0 * HEADS1 + h];
      const float sv1 = s1[sj1 * HEADS1 + h];
      // ---- B: row gathers for slots 0..15 (younger; stay in flight during C)
      const int ps0 = src_sorted[base + min(es, c1)];
      const int ps1 = src_sorted[base + min(4 + es, c1)];
      const int ps2 = src_sorted[base + min(8 + es, c1)];
      const int ps3 = src_sorted[base + min(12 + es, c1)];
      const uint4 pf0 = h1v[(unsigned)(ps0 << 4) + cl];
      const uint4 pf1 = h1v[(unsigned)(ps1 << 4) + cl];
      const uint4 pf2 = h1v[(unsigned)(ps2 << 4) + cl];
      const uint4 pf3 = h1v[(unsigned)(ps3 << 4) + cl];
      // ---- C: weights for slots 0..15 (waits only for sv0/sv1)
      const float w0 = (j0 < cnt) ? __expf(lrelu(sv0 + dv)) : 0.f;
      const float w1 = (j1 < cnt) ? __expf(lrelu(sv1 + dv)) : 0.f;
      z += w0 + w1;
      // ---- C': tail weights -> LDS (slots 16..63; rare)
      const int rmax = (cnt + 7) >> 3;   // wave-uniform
      for (int r = 2; r < rmax; ++r) {
        const int j = (r << 3) + le;
        float w = 0.f;
        if (j < cnt) w = __expf(lrelu(s1[src_sorted[base + j] * HEADS1 + h] + dv));
        wlds[wv][j][h] = w;
        z += w;
      }
      // ---- D: consume prefetched rows (slots 0..15); weights via shuffle
      {
        const float wA = __shfl(w0, (es << 3) | hh);          // slot es
        const float wB = __shfl(w0, ((4 + es) << 3) | hh);    // slot 4+es
        const __half2* pA = (const __half2*)&pf0;
        const __half2* pB = (const __half2*)&pf1;
#pragma unroll
        for (int k = 0; k < 4; ++k) {
          float2 a2 = __half22float2(pA[k]);
          float2 b2v = __half22float2(pB[k]);
          acc[2 * k]     += wA * a2.x + wB * b2v.x;
          acc[2 * k + 1] += wA * a2.y + wB * b2v.y;
        }
      }
      if (cnt > 8) {
        const float wA = __shfl(w1, (es << 3) | hh);          // slot 8+es
        const float wB = __shfl(w1, ((4 + es) << 3) | hh);    // slot 12+es
        const __half2* pA = (const __half2*)&pf2;
        const __half2* pB = (const __half2*)&pf3;
#pragma unroll
        for (int k = 0; k < 4; ++k) {
          float2 a2 = __half22float2(pA[k]);
          float2 b2v = __half22float2(pB[k]);
          acc[2 * k]     += wA * a2.x + wB * b2v.x;
          acc[2 * k + 1] += wA * a2.y + wB * b2v.y;
        }
      }
      // ---- E: remaining slots (deg > 16 within this chunk; rare) via LDS
      for (int i = 16; i < cnt; i += 8) {
        const int jA = i + es, jB = i + 4 + es;
        const float wA = wlds[wv][jA][hh];
        const float wB = wlds[wv][jB][hh];
        const int sA = src_sorted[base + min(jA, c1)];
        const int sB = src_sorted[base + min(jB, c1)];
        const uint4 fA = h1v[(unsigned)(sA << 4) + cl];
        const uint4 fB = h1v[(unsigned)(sB << 4) + cl];
        const __half2* pA = (const __half2*)&fA;
        const __half2* pB = (const __half2*)&fB;
#pragma unroll
        for (int k = 0; k < 4; ++k) {
          float2 a2 = __half22float2(pA[k]);
          float2 b2v = __half22float2(pB[k]);
          acc[2 * k]     += wA * a2.x + wB * b2v.x;
          acc[2 * k + 1] += wA * a2.y + wB * b2v.y;
        }
      }
    }
    // finalize: z per (le,h) partial; reduce over le (lanes with same h)
    z += __shfl_xor(z, 8); z += __shfl_xor(z, 16); z += __shfl_xor(z, 32);
    const float zsel = __shfl(z, hh);   // lane hh holds head hh's total
#pragma unroll
    for (int k = 0; k < 8; ++k) {
      acc[k] += __shfl_xor(acc[k], 16);
      acc[k] += __shfl_xor(acc[k], 32);
    }
    if (es == 0) {
      const float zinv = 1.f / (zsel + 1e-16f);
      __half2 o[4];
#pragma unroll
      for (int k = 0; k < 4; ++k) {
        float ox = acc[2 * k] * zinv + b1[(cl << 3) + 2 * k];
        float oy = acc[2 * k + 1] * zinv + b1[(cl << 3) + 2 * k + 1];
        ox = ox > 0.f ? ox : expm1f(ox);
        oy = oy > 0.f ? oy : expm1f(oy);
        o[k] = __floats2half2_rn(ox, oy);
      }
      ((uint4*)x2h)[(unsigned)(n << 4) + cl] = *(const uint4*)o;
    }
  }
}

// layer2: one wave per node (grid-stride), 1 head. s2 gather issued FIRST
// (oldest), then the row prefetches -> exp overlaps with row fetch.
__global__ __launch_bounds__(256) void layer2_agg(
    const int* __restrict__ row_start, const int* __restrict__ src_sorted,
    const float* __restrict__ s2, const float* __restrict__ d2,
    const __half* __restrict__ h2, const float* __restrict__ b2,
    float* __restrict__ out, int N) {
  const int wv = threadIdx.x >> 6;
  const int lane = threadIdx.x & 63;
  const int es = lane >> 3, cl = lane & 7;
  const uint4* __restrict__ h2v = (const uint4*)h2;
  const int waveId = blockIdx.x * 4 + wv;
  const int stride = gridDim.x * 4;
  for (int n = waveId; n < N; n += stride) {
    const int lo = row_start[n], hi = row_start[n + 1];
    const float dv = d2[n];
    float z = 0.f;
    float acc[8] = {0.f, 0.f, 0.f, 0.f, 0.f, 0.f, 0.f, 0.f};
    for (int base = lo; base < hi; base += 64) {
      const int cnt = min(64, hi - base);
      const int c1 = cnt - 1;
      // ---- A: logit-input gather (oldest)
      const int sidx = src_sorted[base + min(lane, c1)];
      const float sval = s2[sidx];
      // ---- B: clamped in-segment row prefetch, first 32 slots (younger)
      const int ps0 = src_sorted[base + min(es, c1)];
      const int ps1 = src_sorted[base + min(8 + es, c1)];
      const int ps2 = src_sorted[base + min(16 + es, c1)];
      const int ps3 = src_sorted[base + min(24 + es, c1)];
      const uint4 pf0 = h2v[(unsigned)(ps0 << 3) + cl];
      const uint4 pf1 = h2v[(unsigned)(ps1 << 3) + cl];
      const uint4 pf2 = h2v[(unsigned)(ps2 << 3) + cl];
      const uint4 pf3 = h2v[(unsigned)(ps3 << 3) + cl];
      // ---- C: weight (waits only for sval; rows still in flight)
      const float w = (lane < cnt) ? __expf(lrelu(sval + dv)) : 0.f;
      z += w;
      // ---- D: consume prefetched (slots 0..31)
      {
        const float wA = __shfl(w, es);
        const float wB = __shfl(w, 8 + es);
        const __half2* pA = (const __half2*)&pf0;
        const __half2* pB = (const __half2*)&pf1;
#pragma unroll
        for (int k = 0; k < 4; ++k) {
          float2 a2 = __half22float2(pA[k]);
          float2 b2v = __half22float2(pB[k]);
          acc[2 * k]     += wA * a2.x + wB * b2v.x;
          acc[2 * k + 1] += wA * a2.y + wB * b2v.y;
        }
      }
      if (cnt > 16) {
        const float wA = __shfl(w, 16 + es);
        const float wB = __shfl(w, 24 + es);
        const __half2* pA = (const __half2*)&pf2;
        const __half2* pB = (const __half2*)&pf3;
#pragma unroll
        for (int k = 0; k < 4; ++k) {
          float2 a2 = __half22float2(pA[k]);
          float2 b2v = __half22float2(pB[k]);
          acc[2 * k]     += wA * a2.x + wB * b2v.x;
          acc[2 * k + 1] += wA * a2.y + wB * b2v.y;
        }
      }
      // ---- E: remaining slots (deg > 32 within this chunk; rare)
      for (int i = 32; i < cnt; i += 16) {   // wave-uniform
        const int jA = i + es, jB = i + 8 + es;
        const float wA = __shfl(w, jA);
        const float wB = __shfl(w, jB);
        const int sA = src_sorted[base + min(jA, c1)];
        const int sB = src_sorted[base + min(jB, c1)];
        const uint4 fA = h2v[(unsigned)(sA << 3) + cl];
        const uint4 fB = h2v[(unsigned)(sB << 3) + cl];
        const __half2* pA = (const __half2*)&fA;
        const __half2* pB = (const __half2*)&fB;
#pragma unroll
        for (int k = 0; k < 4; ++k) {
          float2 a2 = __half22float2(pA[k]);
          float2 b2v = __half22float2(pB[k]);
          acc[2 * k]     += wA * a2.x + wB * b2v.x;
          acc[2 * k + 1] += wA * a2.y + wB * b2v.y;
        }
      }
    }
#pragma unroll
    for (int off = 1; off < 64; off <<= 1) z += __shfl_xor(z, off);
#pragma unroll
    for (int k = 0; k < 8; ++k) {
      acc[k] += __shfl_xor(acc[k], 8);
      acc[k] += __shfl_xor(acc[k], 16);
      acc[k] += __shfl_xor(acc[k], 32);
    }
    if (es == 0) {
      const float zinv = 1.f / (z + 1e-16f);
      float4 o0, o1;
      o0.x = acc[0] * zinv + b2[(cl << 3) + 0];
      o0.y = acc[1] * zinv + b2[(cl << 3) + 1];
      o0.z = acc[2] * zinv + b2[(cl << 3) + 2];
      o0.w = acc[3] * zinv + b2[(cl << 3) + 3];
      o1.x = acc[4] * zinv + b2[(cl << 3) + 4];
      o1.y = acc[5] * zinv + b2[(cl << 3) + 5];
      o1.z = acc[6] * zinv + b2[(cl << 3) + 6];
      o1.w = acc[7] * zinv + b2[(cl << 3) + 7];
      float4* po = (float4*)&out[(unsigned)(n << 6) + (cl << 3)];
      po[0] = o0;
      po[1] = o1;
    }
  }
}

extern "C" void kernel_launch(void* const* d_in, const int* in_sizes, int n_in,
                              void* d_out, int out_size, void* d_ws, size_t ws_size,
                              hipStream_t stream) {
  const float* x      = (const float*)d_in[0];
  const int*   ei     = (const int*)d_in[1];
  const float* W1     = (const float*)d_in[2];
  const float* a_src1 = (const float*)d_in[3];
  const float* a_dst1 = (const float*)d_in[4];
  const float* b1     = (const float*)d_in[5];
  const float* W2     = (const float*)d_in[6];
  const float* a_src2 = (const float*)d_in[7];
  const float* a_dst2 = (const float*)d_in[8];
  const float* b2     = (const float*)d_in[9];
  float* out = (float*)d_out;

  const int N = in_sizes[0] / INCH;
  const int E = in_sizes[1] / 2;
  const int* src = ei;
  const int* dst = ei + E;

  // Workspace layout (~46 MB; >=71 MB proven available)
  float* ws = (float*)d_ws;
  size_t o = 0;
  __half* xh  = (__half*)(ws + o); o += (size_t)N * C1 / 2;   // x fp16
  __half* h1  = (__half*)(ws + o); o += (size_t)N * C1 / 2;   // layer-1 features fp16
  __half* x2h = (__half*)(ws + o); o += (size_t)N * C1 / 2;   // layer-2 input fp16
  float*  s1  = ws + o;            o += (size_t)N * HEADS1;
  float*  d1  = ws + o;            o += (size_t)N * HEADS1;
  __half* W1t = (__half*)(ws + o); o += 128 * 128 / 2;
  __half* W2t = (__half*)(ws + o); o += 64 * 128 / 2;
  int* deg        = (int*)(ws + o); o += N;
  int* cursor     = (int*)(ws + o); o += N;
  int* row_start  = (int*)(ws + o); o += N + 1;
  int* partial    = (int*)(ws + o); o += SB;
  int* src_sorted = (int*)(ws + o); o += E;
  // layer-2 aliases into h1's region (h1 dead after layer1_agg)
  __half* h2 = h1;                                   // N*64 halves
  float*  s2 = (float*)h1 + (size_t)N * 32;          // N floats
  float*  d2 = s2 + N;                               // N floats

  const int EB = (E + 255) / 256;
  const int NB64 = (N + 63) / 64;
  const int total8 = N * C1 / 8;
  const int cvtB = (total8 + 255) / 256;
  const int tB = (128 * 128 + 64 * 128 + 255) / 256;
  const int histB = EB;
  const int AGGB = min((N + 3) / 4, 2048);   // persistent: 2048 blocks = 32 waves/CU

  hipMemsetAsync(deg, 0, (size_t)N * 4, stream);
  hipMemsetAsync(cursor, 0, (size_t)N * 4, stream);

  prep_kernel<<<cvtB + tB + histB, 256, 0, stream>>>(x, xh, W1, W1t, W2, W2t, dst, deg,
                                                     cvtB, tB, total8, E);
  scan1_kernel<<<SB, SB, 0, stream>>>(deg, partial, N);
  scan3_kernel<<<SB, SB, 0, stream>>>(deg, partial, row_start, N);
  fill_kernel<<<EB, 256, 0, stream>>>(src, dst, row_start, cursor, src_sorted, E);

  // Layer 1
  gemm1_mfma<<<NB64, 256, 0, stream>>>(xh, W1t, a_src1, a_dst1, h1, s1, d1, N);
  layer1_agg<<<AGGB, 256, 0, stream>>>(row_start, src_sorted, s1, d1, h1, b1, x2h, N);

  // Layer 2
  gemm2_mfma<<<NB64, 256, 0, stream>>>(x2h, W2t, a_src2, a_dst2, h2, s2, d2, N);
  layer2_agg<<<AGGB, 256, 0, stream>>>(row_start, src_sorted, s2, d2, h2, b2, out, N);
}

// Round 18
// 186.392 us; speedup vs baseline: 1.2118x; 1.0585x over previous
//
#include <hip/hip_runtime.h>
#include <hip/hip_fp16.h>

#define INCH   128
#define HEADS1 8
#define HID1   16
#define C1     128   // HEADS1*HID1
#define C2     64
#define NEG_SLOPE 0.2f
#define SB     256   // scan blocks / threads

using f16x8 = __attribute__((ext_vector_type(8))) _Float16;
using f32x4 = __attribute__((ext_vector_type(4))) float;

__device__ __forceinline__ float lrelu(float v) { return v >= 0.f ? v : NEG_SLOPE * v; }
// byte-offset swizzle within a 256B LDS row (rows are 128 fp16)
__device__ __forceinline__ int swzA(int row, int byteInRow) {
  return (row << 8) | (byteInRow ^ ((row & 15) << 4));
}

// ---------------- fused prep: x->fp16, W transposes->fp16, folded attention
//                  weight tiles B1e/B2e, dst histogram ----------------
// B1e[col][k] (fp16, col-major like W1t): col<8 -> ws1 for head col (s-logit),
// col>=8 -> wd1 for head col-8.  s1 = x @ ws1 by associativity:
// s1[n,h] = sum_c (x@W1)[n,h*16+c]*a_src[h,c] = sum_k x[n,k]*sum_c W1[k,h*16+c]*a_src[h,c].
__global__ void prep_kernel(const float* __restrict__ x, __half* __restrict__ xh,
                            const float* __restrict__ W1, __half* __restrict__ W1t,
                            const float* __restrict__ W2, __half* __restrict__ W2t,
                            const float* __restrict__ a_src1, const float* __restrict__ a_dst1,
                            const float* __restrict__ a_src2, const float* __restrict__ a_dst2,
                            __half* __restrict__ B1e, __half* __restrict__ B2e,
                            const int* __restrict__ dst, int* __restrict__ deg,
                            int cvtB, int tB, int total8, int E) {
  const int b = blockIdx.x, t = threadIdx.x;
  if (b < cvtB) {
    int i = b * 256 + t;
    if (i >= total8) return;
    const float4* p = (const float4*)x + (size_t)i * 2;
    float4 v0 = p[0], v1 = p[1];
    __half2 ha = __floats2half2_rn(v0.x, v0.y);
    __half2 hb = __floats2half2_rn(v0.z, v0.w);
    __half2 hc = __floats2half2_rn(v1.x, v1.y);
    __half2 hd = __floats2half2_rn(v1.z, v1.w);
    uint4 w = { *(unsigned*)&ha, *(unsigned*)&hb, *(unsigned*)&hc, *(unsigned*)&hd };
    ((uint4*)xh)[i] = w;
  } else if (b < cvtB + tB) {
    int id = (b - cvtB) * 256 + t;
    if (id < 16384) {                      // W1t: [128 cols][128 k]
      int col = id >> 7, k = id & 127;
      W1t[id] = __float2half(W1[k * 128 + col]);
    } else if (id < 24576) {               // W2t: [64 cols][128 k]
      int idx = id - 16384;
      int col = idx >> 7, k = idx & 127;
      W2t[idx] = __float2half(W2[k * 64 + col]);
    } else if (id < 26624) {               // B1e: [16 cols][128 k]
      int idx = id - 24576;
      int col = idx >> 7, k = idx & 127;
      const float* av = (col < 8) ? a_src1 : a_dst1;
      int hh = col & 7;
      float s = 0.f;
#pragma unroll
      for (int c = 0; c < 16; ++c) s += W1[k * 128 + hh * 16 + c] * av[hh * 16 + c];
      B1e[col * 128 + k] = __float2half(s);
    } else if (id < 28672) {               // B2e: [16 cols][128 k], cols 2..15 zero
      int idx = id - 26624;
      int col = idx >> 7, k = idx & 127;
      float s = 0.f;
      if (col == 0) {
#pragma unroll
        for (int c = 0; c < 64; ++c) s += W2[k * 64 + c] * a_src2[c];
      } else if (col == 1) {
#pragma unroll
        for (int c = 0; c < 64; ++c) s += W2[k * 64 + c] * a_dst2[c];
      }
      B2e[col * 128 + k] = __float2half(s);
    }
  } else {
    int e = (b - cvtB - tB) * 256 + t;
    if (e < E) atomicAdd(&deg[dst[e]], 1);
  }
}

// ---------------- CSR build (by destination) ----------------

__global__ void scan1_kernel(const int* __restrict__ deg, int* __restrict__ partial,
                             int* __restrict__ cursor, int N) {
  __shared__ int sh[SB];
  const int b = blockIdx.x, t = threadIdx.x;
  const int chunk = (N + SB - 1) / SB;
  const int lo = b * chunk, hi = min(lo + chunk, N);
  int s = 0;
  for (int i = lo + t; i < hi; i += SB) {
    s += deg[i];
    cursor[i] = 0;
  }
  sh[t] = s;
  __syncthreads();
  for (int off = SB / 2; off; off >>= 1) {
    if (t < off) sh[t] += sh[t + off];
    __syncthreads();
  }
  if (t == 0) partial[b] = sh[0];
}

// stage 2+3 fused: each block locally scans the 256 partials, then scans its chunk.
__global__ void scan3_kernel(const int* __restrict__ deg, const int* __restrict__ partial,
                             int* __restrict__ row_start, int N) {
  __shared__ int pref[SB];
  __shared__ int sh[SB];
  const int b = blockIdx.x, t = threadIdx.x;
  int pv = partial[t];
  pref[t] = pv;
  __syncthreads();
  for (int off = 1; off < SB; off <<= 1) {
    int u = (t >= off) ? pref[t - off] : 0;
    __syncthreads();
    pref[t] += u;
    __syncthreads();
  }
  const int chunk = (N + SB - 1) / SB;
  const int lo = b * chunk, hi = min(lo + chunk, N);
  int run = (b == 0) ? 0 : pref[b - 1];
  for (int base = lo; base < hi; base += SB) {
    int i = base + t;
    int v = (i < hi) ? deg[i] : 0;
    sh[t] = v;
    __syncthreads();
    for (int off = 1; off < SB; off <<= 1) {
      int u = (t >= off) ? sh[t - off] : 0;
      __syncthreads();
      sh[t] += u;
      __syncthreads();
    }
    if (i < hi) row_start[i] = run + sh[t] - v;
    run += sh[SB - 1];
    __syncthreads();
  }
  if (b == SB - 1 && t == 0) row_start[N] = run;
}

__global__ void fill_kernel(const int* __restrict__ src, const int* __restrict__ dst,
                            const int* __restrict__ row_start, int* __restrict__ cursor,
                            int* __restrict__ src_sorted, int E) {
  int e = blockIdx.x * blockDim.x + threadIdx.x;
  if (e >= E) return;
  int d = dst[e];
  int slot = row_start[d] + atomicAdd(&cursor[d], 1);
  src_sorted[slot] = src[e];
}

// ---------------- MFMA GEMMs ----------------
// gemm1: [M x 128] x [128 x (128 + 16ext)]; ct 0..7 -> h1, ct 8 (B1e) -> s1/d1.
__global__ __launch_bounds__(256) void gemm1_mfma(
    const __half* __restrict__ xh, const __half* __restrict__ W1t,
    const __half* __restrict__ B1e,
    __half* __restrict__ h1, float* __restrict__ s1, float* __restrict__ d1, int M) {
  __shared__ unsigned char As[16384];   // 64 x 128 fp16, swizzled
  __shared__ unsigned char Bs[36864];   // 128 cols W1t (32KB) + 16 cols B1e (4KB)
  const int t = threadIdx.x;
  const int m0 = blockIdx.x * 64;
  for (int c = t; c < 1024; c += 256) {
    int row = c >> 4, seg = c & 15;
    int gr = m0 + row;
    uint4 v = make_uint4(0, 0, 0, 0);
    if (gr < M) v = ((const uint4*)xh)[(unsigned)(gr << 4) + seg];
    *(uint4*)(As + swzA(row, seg << 4)) = v;
  }
  for (int c = t; c < 2304; c += 256) {
    int row = c >> 4, seg = c & 15;
    if (row < 128) {
      uint4 v = ((const uint4*)W1t)[(row << 4) + seg];
      *(uint4*)(Bs + swzA(row, seg << 4)) = v;
    } else {
      uint4 v = ((const uint4*)B1e)[((row - 128) << 4) + seg];
      *(uint4*)(Bs + 32768 + swzA(row - 128, seg << 4)) = v;
    }
  }
  __syncthreads();
  const int l = t & 63, wid = t >> 6;
  const int c16 = l & 15;
  const int kOff = (l >> 4) << 4;
  const int rA = (wid << 4) | c16;
  f16x8 a[4];
#pragma unroll
  for (int kb = 0; kb < 4; ++kb)
    a[kb] = *(const f16x8*)(As + swzA(rA, (kb << 6) + kOff));
#pragma unroll
  for (int ct = 0; ct < 9; ++ct) {
    const unsigned char* bbase = (ct < 8) ? Bs : (Bs + 32768);
    const int rB = (ct < 8) ? ((ct << 4) | c16) : c16;
    f32x4 acc = {0.f, 0.f, 0.f, 0.f};
#pragma unroll
    for (int kb = 0; kb < 4; ++kb) {
      f16x8 b = *(const f16x8*)(bbase + swzA(rB, (kb << 6) + kOff));
      acc = __builtin_amdgcn_mfma_f32_16x16x32_f16(a[kb], b, acc, 0, 0, 0);
    }
    if (ct < 8) {
      const int colg = (ct << 4) + c16;
#pragma unroll
      for (int i = 0; i < 4; ++i) {
        const int n = m0 + (wid << 4) + ((l >> 4) << 2) + i;
        if (n < M) h1[(unsigned)(n << 7) + colg] = __float2half(acc[i]);
      }
    } else {
#pragma unroll
      for (int i = 0; i < 4; ++i) {
        const int n = m0 + (wid << 4) + ((l >> 4) << 2) + i;
        if (n < M) {
          if (c16 < 8) s1[n * HEADS1 + c16] = acc[i];
          else         d1[n * HEADS1 + (c16 - 8)] = acc[i];
        }
      }
    }
  }
}

// gemm2: [M x 128] x [128 x (64 + 16ext)]; ct 0..3 -> h2, ct 4 (B2e) -> s2/d2.
__global__ __launch_bounds__(256) void gemm2_mfma(
    const __half* __restrict__ x2h, const __half* __restrict__ W2t,
    const __half* __restrict__ B2e,
    __half* __restrict__ h2, float* __restrict__ s2, float* __restrict__ d2, int M) {
  __shared__ unsigned char As[16384];   // 64 x 128 fp16
  __shared__ unsigned char Bs[20480];   // 64 cols W2t (16KB) + 16 cols B2e (4KB)
  const int t = threadIdx.x;
  const int m0 = blockIdx.x * 64;
  for (int c = t; c < 1024; c += 256) {
    int row = c >> 4, seg = c & 15;
    int gr = m0 + row;
    uint4 v = make_uint4(0, 0, 0, 0);
    if (gr < M) v = ((const uint4*)x2h)[(unsigned)(gr << 4) + seg];
    *(uint4*)(As + swzA(row, seg << 4)) = v;
  }
  for (int c = t; c < 1280; c += 256) {
    int row = c >> 4, seg = c & 15;
    if (row < 64) {
      uint4 v = ((const uint4*)W2t)[(row << 4) + seg];
      *(uint4*)(Bs + swzA(row, seg << 4)) = v;
    } else {
      uint4 v = ((const uint4*)B2e)[((row - 64) << 4) + seg];
      *(uint4*)(Bs + 16384 + swzA(row - 64, seg << 4)) = v;
    }
  }
  __syncthreads();
  const int l = t & 63, wid = t >> 6;
  const int c16 = l & 15;
  const int kOff = (l >> 4) << 4;
  const int rA = (wid << 4) | c16;
  f16x8 a[4];
#pragma unroll
  for (int kb = 0; kb < 4; ++kb)
    a[kb] = *(const f16x8*)(As + swzA(rA, (kb << 6) + kOff));
#pragma unroll
  for (int ct = 0; ct < 5; ++ct) {
    const unsigned char* bbase = (ct < 4) ? Bs : (Bs + 16384);
    const int rB = (ct < 4) ? ((ct << 4) | c16) : c16;
    f32x4 acc = {0.f, 0.f, 0.f, 0.f};
#pragma unroll
    for (int kb = 0; kb < 4; ++kb) {
      f16x8 b = *(const f16x8*)(bbase + swzA(rB, (kb << 6) + kOff));
      acc = __builtin_amdgcn_mfma_f32_16x16x32_f16(a[kb], b, acc, 0, 0, 0);
    }
    if (ct < 4) {
      const int colg = (ct << 4) + c16;
#pragma unroll
      for (int i = 0; i < 4; ++i) {
        const int n = m0 + (wid << 4) + ((l >> 4) << 2) + i;
        if (n < M) h2[(unsigned)(n << 6) + colg] = __float2half(acc[i]);
      }
    } else {
#pragma unroll
      for (int i = 0; i < 4; ++i) {
        const int n = m0 + (wid << 4) + ((l >> 4) << 2) + i;
        if (n < M) {
          if (c16 == 0) s2[n] = acc[i];
          else if (c16 == 1) d2[n] = acc[i];
        }
      }
    }
  }
}

// ---------------- Fused softmax + wide aggregation (unchanged from R17) ----------------
__global__ __launch_bounds__(256) void layer1_agg(
    const int* __restrict__ row_start, const int* __restrict__ src_sorted,
    const float* __restrict__ s1, const float* __restrict__ d1,
    const __half* __restrict__ h1, const float* __restrict__ b1,
    __half* __restrict__ x2h, int N) {
  __shared__ float wlds[4][64][8];   // [wave][slot][head] (tail slots >=16 only)
  const int wv = threadIdx.x >> 6;
  const int lane = threadIdx.x & 63;
  const int le = lane >> 3, h = lane & 7;     // phase 1
  const int es = lane >> 4, cl = lane & 15;   // phase 2
  const int hh = cl >> 1;
  const uint4* __restrict__ h1v = (const uint4*)h1;
  const int waveId = blockIdx.x * 4 + wv;
  const int stride = gridDim.x * 4;
  for (int n = waveId; n < N; n += stride) {
    const int lo = row_start[n], hi = row_start[n + 1];
    const float dv = d1[n * HEADS1 + h];
    float z = 0.f;
    float acc[8] = {0.f, 0.f, 0.f, 0.f, 0.f, 0.f, 0.f, 0.f};
    for (int base = lo; base < hi; base += 64) {
      const int cnt = min(64, hi - base);
      const int c1 = cnt - 1;
      // ---- A: logit-input gathers for slots 0..15 (issued FIRST = oldest)
      const int j0 = le, j1 = 8 + le;
      const int sj0 = src_sorted[base + min(j0, c1)];
      const int sj1 = src_sorted[base + min(j1, c1)];
      const float sv0 = s1[sj0 * HEADS1 + h];
      const float sv1 = s1[sj1 * HEADS1 + h];
      // ---- B: row gathers for slots 0..15 (younger; stay in flight during C)
      const int ps0 = src_sorted[base + min(es, c1)];
      const int ps1 = src_sorted[base + min(4 + es, c1)];
      const int ps2 = src_sorted[base + min(8 + es, c1)];
      const int ps3 = src_sorted[base + min(12 + es, c1)];
      const uint4 pf0 = h1v[(unsigned)(ps0 << 4) + cl];
      const uint4 pf1 = h1v[(unsigned)(ps1 << 4) + cl];
      const uint4 pf2 = h1v[(unsigned)(ps2 << 4) + cl];
      const uint4 pf3 = h1v[(unsigned)(ps3 << 4) + cl];
      // ---- C: weights for slots 0..15 (waits only for sv0/sv1)
      const float w0 = (j0 < cnt) ? __expf(lrelu(sv0 + dv)) : 0.f;
      const float w1 = (j1 < cnt) ? __expf(lrelu(sv1 + dv)) : 0.f;
      z += w0 + w1;
      // ---- C': tail weights -> LDS (slots 16..63; rare)
      const int rmax = (cnt + 7) >> 3;   // wave-uniform
      for (int r = 2; r < rmax; ++r) {
        const int j = (r << 3) + le;
        float w = 0.f;
        if (j < cnt) w = __expf(lrelu(s1[src_sorted[base + j] * HEADS1 + h] + dv));
        wlds[wv][j][h] = w;
        z += w;
      }
      // ---- D: consume prefetched rows (slots 0..15); weights via shuffle
      {
        const float wA = __shfl(w0, (es << 3) | hh);          // slot es
        const float wB = __shfl(w0, ((4 + es) << 3) | hh);    // slot 4+es
        const __half2* pA = (const __half2*)&pf0;
        const __half2* pB = (const __half2*)&pf1;
#pragma unroll
        for (int k = 0; k < 4; ++k) {
          float2 a2 = __half22float2(pA[k]);
          float2 b2v = __half22float2(pB[k]);
          acc[2 * k]     += wA * a2.x + wB * b2v.x;
          acc[2 * k + 1] += wA * a2.y + wB * b2v.y;
        }
      }
      if (cnt > 8) {
        const float wA = __shfl(w1, (es << 3) | hh);          // slot 8+es
        const float wB = __shfl(w1, ((4 + es) << 3) | hh);    // slot 12+es
        const __half2* pA = (const __half2*)&pf2;
        const __half2* pB = (const __half2*)&pf3;
#pragma unroll
        for (int k = 0; k < 4; ++k) {
          float2 a2 = __half22float2(pA[k]);
          float2 b2v = __half22float2(pB[k]);
          acc[2 * k]     += wA * a2.x + wB * b2v.x;
          acc[2 * k + 1] += wA * a2.y + wB * b2v.y;
        }
      }
      // ---- E: remaining slots (deg > 16 within this chunk; rare) via LDS
      for (int i = 16; i < cnt; i += 8) {
        const int jA = i + es, jB = i + 4 + es;
        const float wA = wlds[wv][jA][hh];
        const float wB = wlds[wv][jB][hh];
        const int sA = src_sorted[base + min(jA, c1)];
        const int sB = src_sorted[base + min(jB, c1)];
        const uint4 fA = h1v[(unsigned)(sA << 4) + cl];
        const uint4 fB = h1v[(unsigned)(sB << 4) + cl];
        const __half2* pA = (const __half2*)&fA;
        const __half2* pB = (const __half2*)&fB;
#pragma unroll
        for (int k = 0; k < 4; ++k) {
          float2 a2 = __half22float2(pA[k]);
          float2 b2v = __half22float2(pB[k]);
          acc[2 * k]     += wA * a2.x + wB * b2v.x;
          acc[2 * k + 1] += wA * a2.y + wB * b2v.y;
        }
      }
    }
    // finalize: z per (le,h) partial; reduce over le (lanes with same h)
    z += __shfl_xor(z, 8); z += __shfl_xor(z, 16); z += __shfl_xor(z, 32);
    const float zsel = __shfl(z, hh);   // lane hh holds head hh's total
#pragma unroll
    for (int k = 0; k < 8; ++k) {
      acc[k] += __shfl_xor(acc[k], 16);
      acc[k] += __shfl_xor(acc[k], 32);
    }
    if (es == 0) {
      const float zinv = 1.f / (zsel + 1e-16f);
      __half2 o[4];
#pragma unroll
      for (int k = 0; k < 4; ++k) {
        float ox = acc[2 * k] * zinv + b1[(cl << 3) + 2 * k];
        float oy = acc[2 * k + 1] * zinv + b1[(cl << 3) + 2 * k + 1];
        ox = ox > 0.f ? ox : expm1f(ox);
        oy = oy > 0.f ? oy : expm1f(oy);
        o[k] = __floats2half2_rn(ox, oy);
      }
      ((uint4*)x2h)[(unsigned)(n << 4) + cl] = *(const uint4*)o;
    }
  }
}

__global__ __launch_bounds__(256) void layer2_agg(
    const int* __restrict__ row_start, const int* __restrict__ src_sorted,
    const float* __restrict__ s2, const float* __restrict__ d2,
    const __half* __restrict__ h2, const float* __restrict__ b2,
    float* __restrict__ out, int N) {
  const int wv = threadIdx.x >> 6;
  const int lane = threadIdx.x & 63;
  const int es = lane >> 3, cl = lane & 7;
  const uint4* __restrict__ h2v = (const uint4*)h2;
  const int waveId = blockIdx.x * 4 + wv;
  const int stride = gridDim.x * 4;
  for (int n = waveId; n < N; n += stride) {
    const int lo = row_start[n], hi = row_start[n + 1];
    const float dv = d2[n];
    float z = 0.f;
    float acc[8] = {0.f, 0.f, 0.f, 0.f, 0.f, 0.f, 0.f, 0.f};
    for (int base = lo; base < hi; base += 64) {
      const int cnt = min(64, hi - base);
      const int c1 = cnt - 1;
      // ---- A: logit-input gather (oldest)
      const int sidx = src_sorted[base + min(lane, c1)];
      const float sval = s2[sidx];
      // ---- B: clamped in-segment row prefetch, first 32 slots (younger)
      const int ps0 = src_sorted[base + min(es, c1)];
      const int ps1 = src_sorted[base + min(8 + es, c1)];
      const int ps2 = src_sorted[base + min(16 + es, c1)];
      const int ps3 = src_sorted[base + min(24 + es, c1)];
      const uint4 pf0 = h2v[(unsigned)(ps0 << 3) + cl];
      const uint4 pf1 = h2v[(unsigned)(ps1 << 3) + cl];
      const uint4 pf2 = h2v[(unsigned)(ps2 << 3) + cl];
      const uint4 pf3 = h2v[(unsigned)(ps3 << 3) + cl];
      // ---- C: weight (waits only for sval; rows still in flight)
      const float w = (lane < cnt) ? __expf(lrelu(sval + dv)) : 0.f;
      z += w;
      // ---- D: consume prefetched (slots 0..31)
      {
        const float wA = __shfl(w, es);
        const float wB = __shfl(w, 8 + es);
        const __half2* pA = (const __half2*)&pf0;
        const __half2* pB = (const __half2*)&pf1;
#pragma unroll
        for (int k = 0; k < 4; ++k) {
          float2 a2 = __half22float2(pA[k]);
          float2 b2v = __half22float2(pB[k]);
          acc[2 * k]     += wA * a2.x + wB * b2v.x;
          acc[2 * k + 1] += wA * a2.y + wB * b2v.y;
        }
      }
      if (cnt > 16) {
        const float wA = __shfl(w, 16 + es);
        const float wB = __shfl(w, 24 + es);
        const __half2* pA = (const __half2*)&pf2;
        const __half2* pB = (const __half2*)&pf3;
#pragma unroll
        for (int k = 0; k < 4; ++k) {
          float2 a2 = __half22float2(pA[k]);
          float2 b2v = __half22float2(pB[k]);
          acc[2 * k]     += wA * a2.x + wB * b2v.x;
          acc[2 * k + 1] += wA * a2.y + wB * b2v.y;
        }
      }
      // ---- E: remaining slots (deg > 32 within this chunk; rare)
      for (int i = 32; i < cnt; i += 16) {   // wave-uniform
        const int jA = i + es, jB = i + 8 + es;
        const float wA = __shfl(w, jA);
        const float wB = __shfl(w, jB);
        const int sA = src_sorted[base + min(jA, c1)];
        const int sB = src_sorted[base + min(jB, c1)];
        const uint4 fA = h2v[(unsigned)(sA << 3) + cl];
        const uint4 fB = h2v[(unsigned)(sB << 3) + cl];
        const __half2* pA = (const __half2*)&fA;
        const __half2* pB = (const __half2*)&fB;
#pragma unroll
        for (int k = 0; k < 4; ++k) {
          float2 a2 = __half22float2(pA[k]);
          float2 b2v = __half22float2(pB[k]);
          acc[2 * k]     += wA * a2.x + wB * b2v.x;
          acc[2 * k + 1] += wA * a2.y + wB * b2v.y;
        }
      }
    }
#pragma unroll
    for (int off = 1; off < 64; off <<= 1) z += __shfl_xor(z, off);
#pragma unroll
    for (int k = 0; k < 8; ++k) {
      acc[k] += __shfl_xor(acc[k], 8);
      acc[k] += __shfl_xor(acc[k], 16);
      acc[k] += __shfl_xor(acc[k], 32);
    }
    if (es == 0) {
      const float zinv = 1.f / (z + 1e-16f);
      float4 o0, o1;
      o0.x = acc[0] * zinv + b2[(cl << 3) + 0];
      o0.y = acc[1] * zinv + b2[(cl << 3) + 1];
      o0.z = acc[2] * zinv + b2[(cl << 3) + 2];
      o0.w = acc[3] * zinv + b2[(cl << 3) + 3];
      o1.x = acc[4] * zinv + b2[(cl << 3) + 4];
      o1.y = acc[5] * zinv + b2[(cl << 3) + 5];
      o1.z = acc[6] * zinv + b2[(cl << 3) + 6];
      o1.w = acc[7] * zinv + b2[(cl << 3) + 7];
      float4* po = (float4*)&out[(unsigned)(n << 6) + (cl << 3)];
      po[0] = o0;
      po[1] = o1;
    }
  }
}

extern "C" void kernel_launch(void* const* d_in, const int* in_sizes, int n_in,
                              void* d_out, int out_size, void* d_ws, size_t ws_size,
                              hipStream_t stream) {
  const float* x      = (const float*)d_in[0];
  const int*   ei     = (const int*)d_in[1];
  const float* W1     = (const float*)d_in[2];
  const float* a_src1 = (const float*)d_in[3];
  const float* a_dst1 = (const float*)d_in[4];
  const float* b1     = (const float*)d_in[5];
  const float* W2     = (const float*)d_in[6];
  const float* a_src2 = (const float*)d_in[7];
  const float* a_dst2 = (const float*)d_in[8];
  const float* b2     = (const float*)d_in[9];
  float* out = (float*)d_out;

  const int N = in_sizes[0] / INCH;
  const int E = in_sizes[1] / 2;
  const int* src = ei;
  const int* dst = ei + E;

  // Workspace layout (~46 MB; >=71 MB proven available)
  float* ws = (float*)d_ws;
  size_t o = 0;
  __half* xh  = (__half*)(ws + o); o += (size_t)N * C1 / 2;   // x fp16
  __half* h1  = (__half*)(ws + o); o += (size_t)N * C1 / 2;   // layer-1 features fp16
  __half* x2h = (__half*)(ws + o); o += (size_t)N * C1 / 2;   // layer-2 input fp16
  float*  s1  = ws + o;            o += (size_t)N * HEADS1;
  float*  d1  = ws + o;            o += (size_t)N * HEADS1;
  __half* W1t = (__half*)(ws + o); o += 128 * 128 / 2;
  __half* W2t = (__half*)(ws + o); o += 64 * 128 / 2;
  __half* B1e = (__half*)(ws + o); o += 16 * 128 / 2;         // folded s/d weights L1
  __half* B2e = (__half*)(ws + o); o += 16 * 128 / 2;         // folded s/d weights L2
  int* deg        = (int*)(ws + o); o += N;
  int* cursor     = (int*)(ws + o); o += N;
  int* row_start  = (int*)(ws + o); o += N + 1;
  int* partial    = (int*)(ws + o); o += SB;
  int* src_sorted = (int*)(ws + o); o += E;
  // layer-2 aliases into h1's region (h1 dead after layer1_agg)
  __half* h2 = h1;                                   // N*64 halves
  float*  s2 = (float*)h1 + (size_t)N * 32;          // N floats
  float*  d2 = s2 + N;                               // N floats

  const int EB = (E + 255) / 256;
  const int NB64 = (N + 63) / 64;
  const int total8 = N * C1 / 8;
  const int cvtB = (total8 + 255) / 256;
  const int tB = (16384 + 8192 + 2048 + 2048) / 256;   // 112
  const int histB = EB;
  const int AGGB = min((N + 3) / 4, 2048);   // persistent: 2048 blocks = 32 waves/CU

  hipMemsetAsync(deg, 0, (size_t)N * 4, stream);

  prep_kernel<<<cvtB + tB + histB, 256, 0, stream>>>(
      x, xh, W1, W1t, W2, W2t, a_src1, a_dst1, a_src2, a_dst2, B1e, B2e,
      dst, deg, cvtB, tB, total8, E);
  scan1_kernel<<<SB, SB, 0, stream>>>(deg, partial, cursor, N);
  scan3_kernel<<<SB, SB, 0, stream>>>(deg, partial, row_start, N);
  fill_kernel<<<EB, 256, 0, stream>>>(src, dst, row_start, cursor, src_sorted, E);

  // Layer 1
  gemm1_mfma<<<NB64, 256, 0, stream>>>(xh, W1t, B1e, h1, s1, d1, N);
  layer1_agg<<<AGGB, 256, 0, stream>>>(row_start, src_sorted, s1, d1, h1, b1, x2h, N);

  // Layer 2
  gemm2_mfma<<<NB64, 256, 0, stream>>>(x2h, W2t, B2e, h2, s2, d2, N);
  layer2_agg<<<AGGB, 256, 0, stream>>>(row_start, src_sorted, s2, d2, h2, b2, out, N);
}